// Round 1
// baseline (37423.602 us; speedup 1.0000x reference)
//
#include <hip/hip_runtime.h>
#include <hip/hip_cooperative_groups.h>
#include <cstdint>
#include <cmath>

namespace cg = cooperative_groups;

#define NN_ 2708
#define NF_ 4096
#define MD_ 2048
#define NH_ 1024
#define NC_ 64
#define PITER 100
#define FITER 20

// scal layout (floats in ws): [0]=c [1]=eta [2]=thr(lam/c) [3]=lam [4]=ynormsq [5..24]=rsq[k]

__device__ __forceinline__ float softt(float v, float t) {
    float a = fabsf(v) - t;
    a = a > 0.f ? a : 0.f;
    return copysignf(a, v);
}

__device__ __forceinline__ float blockReduceSum(float v, float* red) {
    int lane = threadIdx.x & 63, wid = threadIdx.x >> 6;
    #pragma unroll
    for (int off = 32; off; off >>= 1) v += __shfl_down(v, off);
    if (lane == 0) red[wid] = v;
    __syncthreads();
    if (wid == 0) {
        int nw = (blockDim.x + 63) >> 6;
        float r = (lane < nw) ? red[lane] : 0.f;
        #pragma unroll
        for (int off = 2; off; off >>= 1) r += __shfl_down(r, off);
        if (lane == 0) red[0] = r;
    }
    __syncthreads();
    float out = red[0];
    __syncthreads();
    return out;
}

// ---------- threefry2x32 + JAX normal init ----------
__device__ __forceinline__ float erfinv_f(float x) {
    float w = -log1pf(-x * x);
    float p;
    if (w < 5.0f) {
        w -= 2.5f;
        p = 2.81022636e-08f;
        p = fmaf(p, w, 3.43273939e-07f);
        p = fmaf(p, w, -3.5233877e-06f);
        p = fmaf(p, w, -4.39150654e-06f);
        p = fmaf(p, w, 0.00021858087f);
        p = fmaf(p, w, -0.00125372503f);
        p = fmaf(p, w, -0.00417768164f);
        p = fmaf(p, w, 0.246640727f);
        p = fmaf(p, w, 1.50140941f);
    } else {
        w = sqrtf(w) - 3.0f;
        p = -0.000200214257f;
        p = fmaf(p, w, 0.000100950558f);
        p = fmaf(p, w, 0.00134934322f);
        p = fmaf(p, w, -0.00367342844f);
        p = fmaf(p, w, 0.00573950773f);
        p = fmaf(p, w, -0.0076224613f);
        p = fmaf(p, w, 0.00943887047f);
        p = fmaf(p, w, 1.00167406f);
        p = fmaf(p, w, 2.83297682f);
    }
    return p * x;
}

__device__ __forceinline__ float u32_to_normal(uint32_t bits) {
    uint32_t fb = (bits >> 9) | 0x3F800000u;
    float f = __uint_as_float(fb) - 1.0f;        // [0,1)
    const float lo = -0.99999994f;               // nextafter(-1,0) in f32
    float u = fmaf(f, 2.0f, lo);                 // f*(hi-lo)+lo, hi-lo rounds to 2.0f
    u = fmaxf(lo, u);
    return 1.41421356f * erfinv_f(u);
}

__global__ void init_x0_kernel(float* __restrict__ X0) {
    int i = blockIdx.x * blockDim.x + threadIdx.x;   // 0..1023 pairs
    if (i >= MD_ / 2) return;
    uint32_t x0 = (uint32_t)i, x1 = (uint32_t)(i + MD_ / 2);
    const uint32_t k0 = 0u, k1 = 1u, k2 = 0x1BD11BDBu;  // 0^1^0x1BD11BDA
    const uint32_t ks[3] = {k0, k1, k2};
    x0 += k0; x1 += k1;
    const int rot[8] = {13, 15, 26, 6, 17, 29, 16, 24};
    #pragma unroll
    for (int g = 0; g < 5; ++g) {
        const int base = (g & 1) ? 4 : 0;
        #pragma unroll
        for (int rr = 0; rr < 4; ++rr) {
            x0 += x1;
            int r = rot[base + rr];
            x1 = (x1 << r) | (x1 >> (32 - r));
            x1 ^= x0;
        }
        x0 += ks[(g + 1) % 3];
        x1 += ks[(g + 2) % 3] + (uint32_t)(g + 1);
    }
    X0[i] = u32_to_normal(x0);
    X0[i + MD_ / 2] = u32_to_normal(x1);
}

__global__ void zero_scal_kernel(float* __restrict__ scal) {
    int t = threadIdx.x;
    if (t < 32) scal[t] = 0.f;
}

__global__ void sumsq_kernel(const float* __restrict__ X, int n, float* __restrict__ acc) {
    __shared__ float red[8];
    float s = 0.f;
    for (size_t i = (size_t)blockIdx.x * blockDim.x + threadIdx.x; i < (size_t)n;
         i += (size_t)gridDim.x * blockDim.x) {
        float v = X[i];
        s += v * v;
    }
    s = blockReduceSum(s, red);
    if (threadIdx.x == 0) atomicAdd(acc, s);
}

// ---------- cooperative power method ----------
__global__ __launch_bounds__(256)
void power_kernel(const float* __restrict__ W, const int* __restrict__ Kp,
                  float* __restrict__ scal, float* __restrict__ Xa, float* __restrict__ Xb) {
    cg::grid_group grid = cg::this_grid();
    __shared__ float xs[MD_];
    __shared__ float tloc[16];
    __shared__ float red[8];
    const int tid = threadIdx.x, bid = blockIdx.x, nb = gridDim.x;
    const int rpb = (NN_ + nb - 1) / nb;                 // 11
    const int r0 = bid * rpb;
    const int r1 = (r0 + rpb < NN_) ? (r0 + rpb) : NN_;
    const int wave = tid >> 6, lane = tid & 63;

    for (int it = 0; it < PITER; ++it) {
        float* Xc = (it & 1) ? Xb : Xa;
        float* Xn = (it & 1) ? Xa : Xb;
        // phase A: stage X, redundant norm, zero Xn share, compute stripe t
        float ss = 0.f;
        for (int k = tid; k < MD_; k += 256) { float v = Xc[k]; xs[k] = v; ss += v * v; }
        __syncthreads();
        ss = blockReduceSum(ss, red);
        float inv_nm = 1.0f / sqrtf(ss);   // normalizing X0 too is scale-invariant for all later iters
        int gz = bid * 256 + tid;
        if (gz < MD_) Xn[gz] = 0.f;
        for (int i = r0 + wave; i < r1; i += 4) {
            const float* Wr = W + (size_t)i * MD_;
            float s = 0.f;
            for (int k = lane; k < MD_; k += 64) s = fmaf(Wr[k], xs[k], s);
            #pragma unroll
            for (int off = 32; off; off >>= 1) s += __shfl_down(s, off);
            if (lane == 0) tloc[i - r0] = s * inv_nm;
        }
        __syncthreads();
        grid.sync();
        // phase B: Xn += t_i * W[i,:] for stripe rows, via atomics
        float acc[8];
        #pragma unroll
        for (int j = 0; j < 8; ++j) acc[j] = 0.f;
        for (int i = r0; i < r1; ++i) {
            float s = tloc[i - r0];
            const float* Wr = W + (size_t)i * MD_;
            #pragma unroll
            for (int j = 0; j < 8; ++j) acc[j] = fmaf(s, Wr[tid + 256 * j], acc[j]);
        }
        #pragma unroll
        for (int j = 0; j < 8; ++j) atomicAdd(&Xn[tid + 256 * j], acc[j]);
        grid.sync();
    }
    if (bid == 0) {
        float* Xf = ((PITER - 1) & 1) ? Xa : Xb;   // buffer written by last iter
        float ss = 0.f;
        for (int k = tid; k < MD_; k += 256) { float v = Xf[k]; ss += v * v; }
        ss = blockReduceSum(ss, red);
        if (tid == 0) {
            float c = sqrtf(ss);
            float lam = (float)Kp[0];
            scal[0] = c;
            scal[1] = 1.0f / c;
            scal[2] = lam / c;
            scal[3] = lam;
        }
    }
}

// ---------- tiled fp32 GEMM with fused epilogues ----------
#define BM 128
#define BN 128
#define BK 16
enum { EPI_NONE = 0, EPI_SOFT2 = 1, EPI_RESID = 2, EPI_FISTA = 3, EPI_BIAS = 4, EPI_BIASRELU = 5 };

template <bool TN>
__global__ __launch_bounds__(256)
void gemm128(const float* __restrict__ A, const float* __restrict__ B,
             int M, int N, int K,
             float* __restrict__ C, float* __restrict__ C2,
             const float* __restrict__ E, const float* __restrict__ bias,
             const float* __restrict__ scal, float betak,
             float* __restrict__ nrm_acc, int epi) {
    __shared__ float As[BK][BM + 4];   // +4 pad: NN transpose-stores go 2-way (free) not 4-way
    __shared__ float Bs[BK][BN];
    const int tid = threadIdx.x;
    const int row0 = blockIdx.y * BM, col0 = blockIdx.x * BN;
    const int tx = tid & 15, ty = tid >> 4;
    float acc[8][8];
    #pragma unroll
    for (int i = 0; i < 8; ++i)
        #pragma unroll
        for (int j = 0; j < 8; ++j) acc[i][j] = 0.f;

    for (int kk = 0; kk < K; kk += BK) {
        if (TN) {
            // A is K x M row-major; As[k][m] = A[kk+k][row0+m]
            #pragma unroll
            for (int l = 0; l < 2; ++l) {
                int fid = tid + 256 * l;
                int r = fid >> 5;               // 0..15
                int c4 = (fid & 31) << 2;       // 0..124
                float4 v = make_float4(0.f, 0.f, 0.f, 0.f);
                if (kk + r < K && row0 + c4 + 3 < M)
                    v = *reinterpret_cast<const float4*>(A + (size_t)(kk + r) * M + row0 + c4);
                *reinterpret_cast<float4*>(&As[r][c4]) = v;
            }
        } else {
            // A is M x K row-major; transpose into As[k][m]
            #pragma unroll
            for (int l = 0; l < 2; ++l) {
                int fid = tid + 256 * l;
                int r = fid >> 2;               // 0..127
                int c4 = (fid & 3) << 2;        // 0,4,8,12
                int gr = row0 + r;
                gr = gr < M ? gr : M - 1;       // clamp: garbage rows masked at store
                float4 v = make_float4(0.f, 0.f, 0.f, 0.f);
                if (kk + c4 < K)                // K%4==0 so float4 fully in-bounds
                    v = *reinterpret_cast<const float4*>(A + (size_t)gr * K + kk + c4);
                As[c4 + 0][r] = v.x; As[c4 + 1][r] = v.y; As[c4 + 2][r] = v.z; As[c4 + 3][r] = v.w;
            }
        }
        #pragma unroll
        for (int l = 0; l < 2; ++l) {
            int fid = tid + 256 * l;
            int r = fid >> 5;
            int c4 = (fid & 31) << 2;
            float4 v = make_float4(0.f, 0.f, 0.f, 0.f);
            if (kk + r < K && col0 + c4 + 3 < N)
                v = *reinterpret_cast<const float4*>(B + (size_t)(kk + r) * N + col0 + c4);
            *reinterpret_cast<float4*>(&Bs[r][c4]) = v;
        }
        __syncthreads();
        #pragma unroll
        for (int k = 0; k < BK; ++k) {
            float4 t0 = *reinterpret_cast<const float4*>(&As[k][ty * 4]);
            float4 t1 = *reinterpret_cast<const float4*>(&As[k][64 + ty * 4]);
            float4 t2 = *reinterpret_cast<const float4*>(&Bs[k][tx * 4]);
            float4 t3 = *reinterpret_cast<const float4*>(&Bs[k][64 + tx * 4]);
            float a[8] = {t0.x, t0.y, t0.z, t0.w, t1.x, t1.y, t1.z, t1.w};
            float b[8] = {t2.x, t2.y, t2.z, t2.w, t3.x, t3.y, t3.z, t3.w};
            #pragma unroll
            for (int i = 0; i < 8; ++i)
                #pragma unroll
                for (int j = 0; j < 8; ++j) acc[i][j] = fmaf(a[i], b[j], acc[i][j]);
        }
        __syncthreads();
    }

    float eta = 0.f, thr = 0.f, lam = 0.f;
    if (epi == EPI_SOFT2) { eta = scal[1]; lam = scal[3]; }
    else if (epi == EPI_FISTA) { eta = scal[1]; thr = scal[2]; }
    float rsq = 0.f;
    #pragma unroll
    for (int i = 0; i < 8; ++i) {
        int r = row0 + ((i < 4) ? ty * 4 + i : 64 + ty * 4 + i - 4);
        if (r < M) {
            #pragma unroll
            for (int j = 0; j < 8; ++j) {
                int c = col0 + ((j < 4) ? tx * 4 + j : 64 + tx * 4 + j - 4);
                if (c < N) {
                    size_t idx = (size_t)r * N + c;
                    float v = acc[i][j];
                    if (epi == EPI_NONE) {
                        C[idx] = v;
                    } else if (epi == EPI_SOFT2) {
                        float s = softt(eta * v, lam);
                        C[idx] = s; C2[idx] = s;
                    } else if (epi == EPI_RESID) {
                        float rr = v - E[idx];
                        C[idx] = rr; rsq = fmaf(rr, rr, rsq);
                    } else if (epi == EPI_FISTA) {
                        float g = E[idx] - eta * v;      // Z - eta*(W^T R)
                        float gn = softt(g, thr);
                        float gold = C[idx];             // previous Gamma
                        C[idx] = gn;                     // Gamma_new
                        C2[idx] = gn + betak * (gn - gold);  // Z_new
                    } else if (epi == EPI_BIAS) {
                        C[idx] = v + bias[c];
                    } else {                             // EPI_BIASRELU
                        float s = v + bias[c];
                        C[idx] = s > 0.f ? s : 0.f;
                    }
                }
            }
        }
    }
    if (epi == EPI_RESID) {
        __syncthreads();
        float tot = blockReduceSum(rsq, &As[0][0]);
        if (tid == 0) atomicAdd(nrm_acc, tot);
    }
}

__global__ void logsoftmax_kernel(const float* __restrict__ O, float* __restrict__ out) {
    int row = blockIdx.x * 4 + (threadIdx.x >> 6);
    int lane = threadIdx.x & 63;
    if (row >= NN_) return;
    float v = O[row * NC_ + lane];
    float m = v;
    #pragma unroll
    for (int off = 32; off; off >>= 1) m = fmaxf(m, __shfl_xor(m, off));
    float e = expf(v - m);
    float s = e;
    #pragma unroll
    for (int off = 32; off; off >>= 1) s += __shfl_xor(s, off);
    out[row * NC_ + lane] = (v - m) - logf(s);
}

__global__ void norms_kernel(const float* __restrict__ scal, float* __restrict__ nout) {
    int k = threadIdx.x;
    if (k < FITER) nout[k] = sqrtf(scal[5 + k]) / sqrtf(scal[4]);
}

static inline void launch_gemm(bool tn, const float* A, const float* B, int M, int N, int K,
                               float* C, float* C2, const float* E, const float* bias,
                               const float* scal, float betak, float* nrm, int epi,
                               hipStream_t s) {
    dim3 grid((N + BN - 1) / BN, (M + BM - 1) / BM), block(256);
    if (tn)
        gemm128<true><<<grid, block, 0, s>>>(A, B, M, N, K, C, C2, E, bias, scal, betak, nrm, epi);
    else
        gemm128<false><<<grid, block, 0, s>>>(A, B, M, N, K, C, C2, E, bias, scal, betak, nrm, epi);
}

extern "C" void kernel_launch(void* const* d_in, const int* in_sizes, int n_in,
                              void* d_out, int out_size, void* d_ws, size_t ws_size,
                              hipStream_t stream) {
    const float* x     = (const float*)d_in[0];   // (2708, 4096)
    const float* adj   = (const float*)d_in[1];   // (2708, 2708)
    const float* gc1_w = (const float*)d_in[2];   // (4096, 1024)
    const float* gc1_b = (const float*)d_in[3];   // (1024,)
    const float* gc2_w = (const float*)d_in[4];   // (1024, 64)
    const float* gc2_b = (const float*)d_in[5];   // (64,)
    const float* Wd    = (const float*)d_in[6];   // (2708, 2048)
    const int*   Kp    = (const int*)d_in[7];     // scalar K

    float* out = (float*)d_out;
    float* logp     = out;                                     // (2708, 64)
    float* x_dec    = logp + (size_t)NN_ * NC_;                // (2708, 4096)
    float* Gamma    = x_dec + (size_t)NN_ * NF_;               // (2048, 4096)
    float* norms_o  = Gamma + (size_t)MD_ * NF_;               // (20,)

    float* wsf  = (float*)d_ws;
    float* scal = wsf;                       // 32
    float* Xa   = scal + 32;                 // 2048
    float* Xb   = Xa + MD_;                  // 2048
    float* Z    = Xb + MD_;                  // 2048*4096
    float* R    = Z + (size_t)MD_ * NF_;     // 2708*4096
    float* xw   = R + (size_t)NN_ * NF_;     // 2708*1024
    float* h    = xw + (size_t)NN_ * NH_;    // 2708*1024
    float* hw   = h + (size_t)NN_ * NH_;     // 2708*64
    float* o    = hw + (size_t)NN_ * NC_;    // 2708*64

    // 1. init: scalars zeroed, X0 from threefry, ||Y||^2
    zero_scal_kernel<<<1, 64, 0, stream>>>(scal);
    init_x0_kernel<<<4, 256, 0, stream>>>(Xa);
    sumsq_kernel<<<1024, 256, 0, stream>>>(x, NN_ * NF_, scal + 4);

    // 2. power method (cooperative, 100 iters, 2 grid syncs each)
    {
        void* args[] = {(void*)&Wd, (void*)&Kp, (void*)&scal, (void*)&Xa, (void*)&Xb};
        hipLaunchCooperativeKernel((void*)power_kernel, dim3(256), dim3(256), args, 0, stream);
    }

    // 3. Gamma0 = soft(eta * W^T Y, lam); Z = Gamma0
    launch_gemm(true, Wd, x, MD_, NF_, NN_, Gamma, Z, nullptr, nullptr, scal, 0.f, nullptr,
                EPI_SOFT2, stream);

    // 4. FISTA iterations; beta_k precomputed in f32 exactly as the reference t-recurrence
    float t = 1.f;
    for (int k = 0; k < FITER; ++k) {
        float tn = (1.0f + sqrtf(1.0f + (4.0f * t) * t)) / 2.0f;
        float beta = (t - 1.0f) / tn;
        t = tn;
        // R = W @ Z - Y ; rsq[k] += ||R||^2
        launch_gemm(false, Wd, Z, NN_, NF_, MD_, R, nullptr, x, nullptr, scal, 0.f,
                    scal + 5 + k, EPI_RESID, stream);
        // U = W^T R ; Gamma = soft(Z - eta U, thr); Z = Gamma_new + beta*(Gamma_new - Gamma_old)
        launch_gemm(true, Wd, R, MD_, NF_, NN_, Gamma, Z, Z, nullptr, scal, beta, nullptr,
                    EPI_FISTA, stream);
    }

    // 5. x_dec = W @ Gamma
    launch_gemm(false, Wd, Gamma, NN_, NF_, MD_, x_dec, nullptr, nullptr, nullptr, scal, 0.f,
                nullptr, EPI_NONE, stream);
    // 6. xw = x_dec @ gc1_w
    launch_gemm(false, x_dec, gc1_w, NN_, NH_, NF_, xw, nullptr, nullptr, nullptr, scal, 0.f,
                nullptr, EPI_NONE, stream);
    // 7. h = relu(adj @ xw + b1)
    launch_gemm(false, adj, xw, NN_, NH_, NN_, h, nullptr, nullptr, gc1_b, scal, 0.f,
                nullptr, EPI_BIASRELU, stream);
    // 8. hw = h @ gc2_w
    launch_gemm(false, h, gc2_w, NN_, NC_, NH_, hw, nullptr, nullptr, nullptr, scal, 0.f,
                nullptr, EPI_NONE, stream);
    // 9. o = adj @ hw + b2
    launch_gemm(false, adj, hw, NN_, NC_, NN_, o, nullptr, nullptr, gc2_b, scal, 0.f,
                nullptr, EPI_BIAS, stream);
    // 10. log_softmax rows -> out0 ; norms -> out3
    logsoftmax_kernel<<<(NN_ + 3) / 4, 256, 0, stream>>>(o, logp);
    norms_kernel<<<1, 32, 0, stream>>>(scal, norms_o);
}

// Round 2
// 15264.211 us; speedup vs baseline: 2.4517x; 2.4517x over previous
//
#include <hip/hip_runtime.h>
#include <hip/hip_cooperative_groups.h>
#include <cstdint>
#include <cmath>

namespace cg = cooperative_groups;

#define NN_ 2708
#define NF_ 4096
#define MD_ 2048
#define NH_ 1024
#define NC_ 64
#define PITER 100
#define FITER 20
#define KPAD 2720   // 2708 padded to multiple of 32

// scal layout (floats in ws): [0]=c [1]=eta [2]=thr(lam/c) [3]=lam [4]=ynormsq [5..24]=rsq[k]

typedef _Float16 half8_t __attribute__((ext_vector_type(8)));
typedef _Float16 half4_t __attribute__((ext_vector_type(4)));
typedef float floatx4_t __attribute__((ext_vector_type(4)));

__device__ __forceinline__ float softt(float v, float t) {
    float a = fabsf(v) - t;
    a = a > 0.f ? a : 0.f;
    return copysignf(a, v);
}

__device__ __forceinline__ float blockReduceSum(float v, float* red) {
    int lane = threadIdx.x & 63, wid = threadIdx.x >> 6;
    #pragma unroll
    for (int off = 32; off; off >>= 1) v += __shfl_down(v, off);
    if (lane == 0) red[wid] = v;
    __syncthreads();
    if (wid == 0) {
        int nw = (blockDim.x + 63) >> 6;
        float r = (lane < nw) ? red[lane] : 0.f;
        #pragma unroll
        for (int off = 2; off; off >>= 1) r += __shfl_down(r, off);
        if (lane == 0) red[0] = r;
    }
    __syncthreads();
    float out = red[0];
    __syncthreads();
    return out;
}

// ---------- threefry2x32 + JAX normal init ----------
__device__ __forceinline__ float erfinv_f(float x) {
    float w = -log1pf(-x * x);
    float p;
    if (w < 5.0f) {
        w -= 2.5f;
        p = 2.81022636e-08f;
        p = fmaf(p, w, 3.43273939e-07f);
        p = fmaf(p, w, -3.5233877e-06f);
        p = fmaf(p, w, -4.39150654e-06f);
        p = fmaf(p, w, 0.00021858087f);
        p = fmaf(p, w, -0.00125372503f);
        p = fmaf(p, w, -0.00417768164f);
        p = fmaf(p, w, 0.246640727f);
        p = fmaf(p, w, 1.50140941f);
    } else {
        w = sqrtf(w) - 3.0f;
        p = -0.000200214257f;
        p = fmaf(p, w, 0.000100950558f);
        p = fmaf(p, w, 0.00134934322f);
        p = fmaf(p, w, -0.00367342844f);
        p = fmaf(p, w, 0.00573950773f);
        p = fmaf(p, w, -0.0076224613f);
        p = fmaf(p, w, 0.00943887047f);
        p = fmaf(p, w, 1.00167406f);
        p = fmaf(p, w, 2.83297682f);
    }
    return p * x;
}

__device__ __forceinline__ float u32_to_normal(uint32_t bits) {
    uint32_t fb = (bits >> 9) | 0x3F800000u;
    float f = __uint_as_float(fb) - 1.0f;        // [0,1)
    const float lo = -0.99999994f;               // nextafter(-1,0) in f32
    float u = fmaf(f, 2.0f, lo);
    u = fmaxf(lo, u);
    return 1.41421356f * erfinv_f(u);
}

__global__ void init_x0_kernel(float* __restrict__ X0) {
    int i = blockIdx.x * blockDim.x + threadIdx.x;   // 0..1023 pairs
    if (i >= MD_ / 2) return;
    uint32_t x0 = (uint32_t)i, x1 = (uint32_t)(i + MD_ / 2);
    const uint32_t k0 = 0u, k1 = 1u, k2 = 0x1BD11BDBu;
    const uint32_t ks[3] = {k0, k1, k2};
    x0 += k0; x1 += k1;
    const int rot[8] = {13, 15, 26, 6, 17, 29, 16, 24};
    #pragma unroll
    for (int g = 0; g < 5; ++g) {
        const int base = (g & 1) ? 4 : 0;
        #pragma unroll
        for (int rr = 0; rr < 4; ++rr) {
            x0 += x1;
            int r = rot[base + rr];
            x1 = (x1 << r) | (x1 >> (32 - r));
            x1 ^= x0;
        }
        x0 += ks[(g + 1) % 3];
        x1 += ks[(g + 2) % 3] + (uint32_t)(g + 1);
    }
    X0[i] = u32_to_normal(x0);
    X0[i + MD_ / 2] = u32_to_normal(x1);
}

__global__ void zero_scal_kernel(float* __restrict__ scal) {
    int t = threadIdx.x;
    if (t < 32) scal[t] = 0.f;
}

__global__ void sumsq_kernel(const float* __restrict__ X, int n, float* __restrict__ acc) {
    __shared__ float red[8];
    float s = 0.f;
    for (size_t i = (size_t)blockIdx.x * blockDim.x + threadIdx.x; i < (size_t)n;
         i += (size_t)gridDim.x * blockDim.x) {
        float v = X[i];
        s += v * v;
    }
    s = blockReduceSum(s, red);
    if (threadIdx.x == 0) atomicAdd(acc, s);
}

// ---------- transpose + split fp32 -> f16 hi/lo, out[c][r] padded to Rpad ----------
__global__ void tsplit_kernel(const float* __restrict__ src, int R, int C, int Rpad,
                              _Float16* __restrict__ hi, _Float16* __restrict__ lo) {
    __shared__ float t[32][33];
    int rb = blockIdx.y * 32, cb = blockIdx.x * 32;
    int tx = threadIdx.x & 31, ty = threadIdx.x >> 5;   // ty 0..7
    #pragma unroll
    for (int s = 0; s < 32; s += 8) {
        int r = rb + ty + s, c = cb + tx;
        t[ty + s][tx] = (r < R) ? src[(size_t)r * C + c] : 0.f;
    }
    __syncthreads();
    #pragma unroll
    for (int s = 0; s < 32; s += 8) {
        int c = cb + ty + s, r = rb + tx;
        float v = t[tx][ty + s];
        _Float16 h = (_Float16)v;
        size_t o = (size_t)c * Rpad + r;
        hi[o] = h;
        lo[o] = (_Float16)(v - (float)h);
    }
}

// ---------- cooperative power method on G = W^T W (symmetric) ----------
__global__ __launch_bounds__(256)
void power_g_kernel(const float* __restrict__ G, const int* __restrict__ Kp,
                    float* __restrict__ scal, float* __restrict__ Xa, float* __restrict__ Xb) {
    cg::grid_group grid = cg::this_grid();
    __shared__ float xs[MD_];
    __shared__ float red[8];
    const int tid = threadIdx.x, bid = blockIdx.x;
    const int w = tid >> 6, l = tid & 63;
    const int jbase = bid * 16;   // 128 blocks x 16 rows = 2048

    for (int it = 0; it < PITER; ++it) {
        const float* Xc = (it & 1) ? Xb : Xa;
        float* Xn = (it & 1) ? Xa : Xb;
        float ss = 0.f;
        for (int k = tid; k < MD_; k += 256) { float v = Xc[k]; xs[k] = v; ss += v * v; }
        __syncthreads();
        ss = blockReduceSum(ss, red);
        float inv = 1.0f / sqrtf(ss);
        // y_j = inv * dot(G[j], xs) ; G symmetric so row reads are contiguous
        for (int jj = w; jj < 16; jj += 4) {
            int j = jbase + jj;
            const float* Gr = G + (size_t)j * MD_;
            float s = 0.f;
            for (int k = l; k < MD_; k += 64) s = fmaf(Gr[k], xs[k], s);
            #pragma unroll
            for (int off = 32; off; off >>= 1) s += __shfl_down(s, off);
            if (l == 0) Xn[j] = s * inv;
        }
        grid.sync();
    }
    if (bid == 0) {
        const float* Xf = ((PITER - 1) & 1) ? Xa : Xb;   // buffer written by last iter
        float ss = 0.f;
        for (int k = tid; k < MD_; k += 256) { float v = Xf[k]; ss += v * v; }
        ss = blockReduceSum(ss, red);
        if (tid == 0) {
            float c = sqrtf(ss);
            float lam = (float)Kp[0];
            scal[0] = c;
            scal[1] = 1.0f / c;
            scal[2] = lam / c;
            scal[3] = lam;
        }
    }
}

// ---------- split-f16 MFMA GEMM (3-product Ootomo), 128x128 tile, BK=32 ----------
enum { ME_STORE = 0, ME_SOFT2 = 1, ME_RESID = 2, ME_FISTA = 3, ME_FISTA_G = 4 };

// stage a 128x32 f16 tile (rows row0.., k-slice kk..) into LDS via global_load_lds width=16
__device__ __forceinline__ void stage_h(const _Float16* __restrict__ g, int row0, int K, int kk,
                                        _Float16* s, int w, int l) {
    #pragma unroll
    for (int p = 0; p < 2; ++p) {
        int c = p * 256 + w * 64 + l;                       // chunk id, lanes contiguous
        const _Float16* gp = g + (size_t)(row0 + (c >> 2)) * K + kk + ((c & 3) << 3);
        _Float16* lp = s + ((size_t)(p * 256 + w * 64) << 3);   // wave-uniform base; HW adds lane*16B
        __builtin_amdgcn_global_load_lds(
            (const __attribute__((address_space(1))) void*)gp,
            (__attribute__((address_space(3))) void*)lp, 16, 0, 0);
    }
}

template <bool AFP32>
__global__ __launch_bounds__(256)
void mgemm_kernel(const _Float16* __restrict__ Ah, const _Float16* __restrict__ Al,
                  const float* __restrict__ Afp, int Marr,
                  const _Float16* __restrict__ Bh, const _Float16* __restrict__ Bl,
                  int M, int N, int K, int Mvalid,
                  float* __restrict__ C,
                  const float* __restrict__ E,
                  _Float16* __restrict__ Th, _Float16* __restrict__ Tl, int Tstride,
                  const float* __restrict__ scal, float betak,
                  float* __restrict__ nrm_acc, int epi) {
    __shared__ __align__(16) _Float16 sAh[128 * 32], sAl[128 * 32];
    __shared__ __align__(16) _Float16 sBh[128 * 32], sBl[128 * 32];
    __shared__ float red[8];
    const int tid = threadIdx.x;
    const int w = tid >> 6, l = tid & 63;
    const int wr = w >> 1, wc = w & 1;
    const int quad = l >> 4, lc = l & 15;
    const int row0 = blockIdx.y * 128, col0 = blockIdx.x * 128;

    floatx4_t acc[4][4];
    #pragma unroll
    for (int i = 0; i < 4; ++i)
        #pragma unroll
        for (int j = 0; j < 4; ++j) {
            floatx4_t z = {0.f, 0.f, 0.f, 0.f};
            acc[i][j] = z;
        }

    for (int kk = 0; kk < K; kk += 32) {
        if constexpr (AFP32) {
            // split fp32 A on the fly (rows clamped to Marr-1; garbage rows masked at store)
            #pragma unroll
            for (int p = 0; p < 4; ++p) {
                int c2 = p * 256 + tid;                 // 0..1023
                int r = c2 >> 3, k4 = (c2 & 7) << 2;
                int gr = row0 + r;
                gr = gr < Marr ? gr : Marr - 1;
                float4 v = *reinterpret_cast<const float4*>(Afp + (size_t)gr * K + kk + k4);
                half4_t hh, ll;
                hh[0] = (_Float16)v.x; ll[0] = (_Float16)(v.x - (float)hh[0]);
                hh[1] = (_Float16)v.y; ll[1] = (_Float16)(v.y - (float)hh[1]);
                hh[2] = (_Float16)v.z; ll[2] = (_Float16)(v.z - (float)hh[2]);
                hh[3] = (_Float16)v.w; ll[3] = (_Float16)(v.w - (float)hh[3]);
                *reinterpret_cast<half4_t*>(&sAh[r * 32 + k4]) = hh;
                *reinterpret_cast<half4_t*>(&sAl[r * 32 + k4]) = ll;
            }
        } else {
            stage_h(Ah, row0, K, kk, sAh, w, l);
            stage_h(Al, row0, K, kk, sAl, w, l);
        }
        stage_h(Bh, col0, K, kk, sBh, w, l);
        stage_h(Bl, col0, K, kk, sBl, w, l);
        asm volatile("s_waitcnt vmcnt(0)" ::: "memory");
        __syncthreads();

        half8_t fAh[4], fAl[4], fBh[4], fBl[4];
        #pragma unroll
        for (int i = 0; i < 4; ++i) {
            int oa = (wr * 64 + i * 16 + lc) * 32 + quad * 8;
            fAh[i] = *reinterpret_cast<const half8_t*>(&sAh[oa]);
            fAl[i] = *reinterpret_cast<const half8_t*>(&sAl[oa]);
            int ob = (wc * 64 + i * 16 + lc) * 32 + quad * 8;
            fBh[i] = *reinterpret_cast<const half8_t*>(&sBh[ob]);
            fBl[i] = *reinterpret_cast<const half8_t*>(&sBl[ob]);
        }
        #pragma unroll
        for (int i = 0; i < 4; ++i)
            #pragma unroll
            for (int j = 0; j < 4; ++j) {
                acc[i][j] = __builtin_amdgcn_mfma_f32_16x16x32_f16(fAh[i], fBh[j], acc[i][j], 0, 0, 0);
                acc[i][j] = __builtin_amdgcn_mfma_f32_16x16x32_f16(fAh[i], fBl[j], acc[i][j], 0, 0, 0);
                acc[i][j] = __builtin_amdgcn_mfma_f32_16x16x32_f16(fAl[i], fBh[j], acc[i][j], 0, 0, 0);
            }
        __syncthreads();
    }

    float eta = 0.f, thr = 0.f, lam = 0.f;
    if (epi == ME_SOFT2) { eta = scal[1]; lam = scal[3]; }
    else if (epi == ME_FISTA || epi == ME_FISTA_G) { eta = scal[1]; thr = scal[2]; }
    float rsq = 0.f;
    #pragma unroll
    for (int i = 0; i < 4; ++i) {
        int grow0 = row0 + wr * 64 + i * 16 + quad * 4;   // Mvalid%4==0 so group all-valid or all-not
        bool rowok = grow0 < Mvalid;
        #pragma unroll
        for (int j = 0; j < 4; ++j) {
            int gcol = col0 + wc * 64 + j * 16 + lc;
            floatx4_t v = acc[i][j];
            if (epi == ME_STORE) {
                if (rowok) {
                    #pragma unroll
                    for (int r = 0; r < 4; ++r) C[(size_t)(grow0 + r) * N + gcol] = v[r];
                }
            } else if (epi == ME_SOFT2) {
                half4_t hh, ll;
                #pragma unroll
                for (int r = 0; r < 4; ++r) {
                    float gm = softt(eta * v[r], lam);
                    C[(size_t)(grow0 + r) * N + gcol] = gm;
                    _Float16 h = (_Float16)gm;
                    hh[r] = h; ll[r] = (_Float16)(gm - (float)h);
                }
                size_t to = (size_t)gcol * Tstride + grow0;
                *reinterpret_cast<half4_t*>(&Th[to]) = hh;
                *reinterpret_cast<half4_t*>(&Tl[to]) = ll;
            } else if (epi == ME_RESID) {
                if (rowok) {
                    half4_t hh, ll;
                    #pragma unroll
                    for (int r = 0; r < 4; ++r) {
                        float rr = v[r] - E[(size_t)(grow0 + r) * N + gcol];
                        rsq = fmaf(rr, rr, rsq);
                        _Float16 h = (_Float16)rr;
                        hh[r] = h; ll[r] = (_Float16)(rr - (float)h);
                    }
                    size_t to = (size_t)gcol * Tstride + grow0;
                    *reinterpret_cast<half4_t*>(&Th[to]) = hh;
                    *reinterpret_cast<half4_t*>(&Tl[to]) = ll;
                }
            } else {  // ME_FISTA / ME_FISTA_G
                size_t to = (size_t)gcol * Tstride + grow0;
                half4_t zh = *reinterpret_cast<const half4_t*>(&Th[to]);
                half4_t zl = *reinterpret_cast<const half4_t*>(&Tl[to]);
                half4_t oh, ol;
                #pragma unroll
                for (int r = 0; r < 4; ++r) {
                    float z = (float)zh[r] + (float)zl[r];
                    float g = z - eta * v[r];
                    float gn = softt(g, thr);
                    size_t ci = (size_t)(grow0 + r) * N + gcol;
                    float gold = C[ci];
                    C[ci] = gn;
                    float zo = (epi == ME_FISTA) ? (gn + betak * (gn - gold)) : gn;
                    _Float16 h = (_Float16)zo;
                    oh[r] = h; ol[r] = (_Float16)(zo - (float)h);
                }
                *reinterpret_cast<half4_t*>(&Th[to]) = oh;
                *reinterpret_cast<half4_t*>(&Tl[to]) = ol;
            }
        }
    }
    if (epi == ME_RESID) {
        float tot = blockReduceSum(rsq, red);
        if (tid == 0) atomicAdd(nrm_acc, tot);
    }
}

static inline void launch_mgemm(const _Float16* Ah, const _Float16* Al,
                                const float* Afp, int Marr,
                                const _Float16* Bh, const _Float16* Bl,
                                int M, int N, int K, int Mvalid, float* C, const float* E,
                                _Float16* Th, _Float16* Tl, int Tstride,
                                const float* scal, float betak, float* nrm, int epi,
                                hipStream_t s) {
    dim3 grid(N / 128, (M + 127) / 128), block(256);
    if (Afp)
        mgemm_kernel<true><<<grid, block, 0, s>>>(Ah, Al, Afp, Marr, Bh, Bl, M, N, K, Mvalid,
                                                  C, E, Th, Tl, Tstride, scal, betak, nrm, epi);
    else
        mgemm_kernel<false><<<grid, block, 0, s>>>(Ah, Al, Afp, Marr, Bh, Bl, M, N, K, Mvalid,
                                                   C, E, Th, Tl, Tstride, scal, betak, nrm, epi);
}

// ---------- fp32 tiled GEMM for the small tail (unchanged from round 1) ----------
#define BM 128
#define BN 128
#define BK 16
enum { EPI_NONE = 0, EPI_BIAS = 4, EPI_BIASRELU = 5 };

__global__ __launch_bounds__(256)
void gemm128(const float* __restrict__ A, const float* __restrict__ B,
             int M, int N, int K,
             float* __restrict__ C, const float* __restrict__ bias, int epi) {
    __shared__ float As[BK][BM + 4];
    __shared__ float Bs[BK][BN];
    const int tid = threadIdx.x;
    const int row0 = blockIdx.y * BM, col0 = blockIdx.x * BN;
    const int tx = tid & 15, ty = tid >> 4;
    float acc[8][8];
    #pragma unroll
    for (int i = 0; i < 8; ++i)
        #pragma unroll
        for (int j = 0; j < 8; ++j) acc[i][j] = 0.f;

    for (int kk = 0; kk < K; kk += BK) {
        #pragma unroll
        for (int lql = 0; lql < 2; ++lql) {
            int fid = tid + 256 * lql;
            int r = fid >> 2;
            int c4 = (fid & 3) << 2;
            int gr = row0 + r;
            gr = gr < M ? gr : M - 1;
            float4 v = make_float4(0.f, 0.f, 0.f, 0.f);
            if (kk + c4 < K)
                v = *reinterpret_cast<const float4*>(A + (size_t)gr * K + kk + c4);
            As[c4 + 0][r] = v.x; As[c4 + 1][r] = v.y; As[c4 + 2][r] = v.z; As[c4 + 3][r] = v.w;
        }
        #pragma unroll
        for (int lql = 0; lql < 2; ++lql) {
            int fid = tid + 256 * lql;
            int r = fid >> 5;
            int c4 = (fid & 31) << 2;
            float4 v = make_float4(0.f, 0.f, 0.f, 0.f);
            if (kk + r < K && col0 + c4 + 3 < N)
                v = *reinterpret_cast<const float4*>(B + (size_t)(kk + r) * N + col0 + c4);
            *reinterpret_cast<float4*>(&Bs[r][c4]) = v;
        }
        __syncthreads();
        #pragma unroll
        for (int k = 0; k < BK; ++k) {
            float4 t0 = *reinterpret_cast<const float4*>(&As[k][ty * 4]);
            float4 t1 = *reinterpret_cast<const float4*>(&As[k][64 + ty * 4]);
            float4 t2 = *reinterpret_cast<const float4*>(&Bs[k][tx * 4]);
            float4 t3 = *reinterpret_cast<const float4*>(&Bs[k][64 + tx * 4]);
            float a[8] = {t0.x, t0.y, t0.z, t0.w, t1.x, t1.y, t1.z, t1.w};
            float b[8] = {t2.x, t2.y, t2.z, t2.w, t3.x, t3.y, t3.z, t3.w};
            #pragma unroll
            for (int i = 0; i < 8; ++i)
                #pragma unroll
                for (int j = 0; j < 8; ++j) acc[i][j] = fmaf(a[i], b[j], acc[i][j]);
        }
        __syncthreads();
    }

    #pragma unroll
    for (int i = 0; i < 8; ++i) {
        int r = row0 + ((i < 4) ? ty * 4 + i : 64 + ty * 4 + i - 4);
        if (r < M) {
            #pragma unroll
            for (int j = 0; j < 8; ++j) {
                int c = col0 + ((j < 4) ? tx * 4 + j : 64 + tx * 4 + j - 4);
                if (c < N) {
                    size_t idx = (size_t)r * N + c;
                    float v = acc[i][j];
                    if (epi == EPI_BIAS) v += bias[c];
                    else if (epi == EPI_BIASRELU) { v += bias[c]; v = v > 0.f ? v : 0.f; }
                    C[idx] = v;
                }
            }
        }
    }
}

__global__ void logsoftmax_kernel(const float* __restrict__ O, float* __restrict__ out) {
    int row = blockIdx.x * 4 + (threadIdx.x >> 6);
    int lane = threadIdx.x & 63;
    if (row >= NN_) return;
    float v = O[row * NC_ + lane];
    float m = v;
    #pragma unroll
    for (int off = 32; off; off >>= 1) m = fmaxf(m, __shfl_xor(m, off));
    float e = expf(v - m);
    float s = e;
    #pragma unroll
    for (int off = 32; off; off >>= 1) s += __shfl_xor(s, off);
    out[row * NC_ + lane] = (v - m) - logf(s);
}

__global__ void norms_kernel(const float* __restrict__ scal, float* __restrict__ nout) {
    int k = threadIdx.x;
    if (k < FITER) nout[k] = sqrtf(scal[5 + k]) / sqrtf(scal[4]);
}

static inline void launch_gemm32(const float* A, const float* B, int M, int N, int K,
                                 float* C, const float* bias, int epi, hipStream_t s) {
    dim3 grid((N + BN - 1) / BN, (M + BM - 1) / BM), block(256);
    gemm128<<<grid, block, 0, s>>>(A, B, M, N, K, C, bias, epi);
}

extern "C" void kernel_launch(void* const* d_in, const int* in_sizes, int n_in,
                              void* d_out, int out_size, void* d_ws, size_t ws_size,
                              hipStream_t stream) {
    const float* x     = (const float*)d_in[0];   // (2708, 4096)
    const float* adj   = (const float*)d_in[1];   // (2708, 2708)
    const float* gc1_w = (const float*)d_in[2];   // (4096, 1024)
    const float* gc1_b = (const float*)d_in[3];   // (1024,)
    const float* gc2_w = (const float*)d_in[4];   // (1024, 64)
    const float* gc2_b = (const float*)d_in[5];   // (64,)
    const float* Wd    = (const float*)d_in[6];   // (2708, 2048)
    const int*   Kp    = (const int*)d_in[7];     // scalar K

    float* out = (float*)d_out;
    float* logp    = out;                                     // (2708, 64)
    float* x_dec   = logp + (size_t)NN_ * NC_;                // (2708, 4096)
    float* Gamma   = x_dec + (size_t)NN_ * NF_;               // (2048, 4096)
    float* norms_o = Gamma + (size_t)MD_ * NF_;               // (20,)

    // ---- ws layout (~100.4 MB, <= round-1's proven footprint) ----
    float* wsf  = (float*)d_ws;
    float* scal = wsf;                      // 32 floats
    float* Xa   = wsf + 32;                 // 2048
    float* Xb   = Xa + MD_;                 // 2048  (ends at 4128 floats; 16B-aligned)
    _Float16* Zt_hi = (_Float16*)(wsf + 4128);          // [4096][2048]
    _Float16* Zt_lo = Zt_hi + (size_t)NF_ * MD_;
    _Float16* Rt_hi = Zt_lo + (size_t)NF_ * MD_;        // [4096][2720] (also hosts xt, then G)
    _Float16* Rt_lo = Rt_hi + (size_t)NF_ * KPAD;
    _Float16* Wt_hi = Rt_lo + (size_t)NF_ * KPAD;       // [2048][2720]
    _Float16* Wt_lo = Wt_hi + (size_t)MD_ * KPAD;
    // region aliases (lifetimes verified: G dead before xt written; Zt/Rt dead before tail)
    float* G    = (float*)Rt_hi;            // 16.78 MB <= 22.28 MB region
    float* xw   = (float*)Zt_hi;            // after x_dec GEMM, Zt is dead
    float* hbuf = (float*)Zt_lo;
    float* hw   = (float*)Rt_hi;            // after FISTA, Rt is dead
    float* obuf = hw + (size_t)NN_ * NC_;

    // 1. init: scalars zeroed, X0 from threefry, ||Y||^2
    zero_scal_kernel<<<1, 64, 0, stream>>>(scal);
    init_x0_kernel<<<4, 256, 0, stream>>>(Xa);
    sumsq_kernel<<<1024, 256, 0, stream>>>(x, NN_ * NF_, scal + 4);

    // 2. Wt = split(W^T) with K padded 2708->2720 (zeros)
    {
        dim3 g(MD_ / 32, KPAD / 32);
        tsplit_kernel<<<g, 256, 0, stream>>>(Wd, NN_, MD_, KPAD, Wt_hi, Wt_lo);
    }
    // 3. G = W^T W (MFMA), then cooperative power iteration on G
    launch_mgemm(Wt_hi, Wt_lo, nullptr, 0, Wt_hi, Wt_lo, MD_, MD_, KPAD, MD_,
                 G, nullptr, nullptr, nullptr, 0, scal, 0.f, nullptr, ME_STORE, stream);
    {
        void* args[] = {(void*)&G, (void*)&Kp, (void*)&scal, (void*)&Xa, (void*)&Xb};
        hipLaunchCooperativeKernel((void*)power_g_kernel, dim3(128), dim3(256), args, 0, stream);
    }
    // 4. xt = split(x^T) into the Rt region (overwrites G — G is dead now)
    {
        dim3 g(NF_ / 32, KPAD / 32);
        tsplit_kernel<<<g, 256, 0, stream>>>(x, NN_, NF_, KPAD, Rt_hi, Rt_lo);
    }
    // 5. Gamma0 = soft(eta * W^T Y, lam); Z = Gamma0 (split into Zt)
    launch_mgemm(Wt_hi, Wt_lo, nullptr, 0, Rt_hi, Rt_lo, MD_, NF_, KPAD, MD_,
                 Gamma, nullptr, Zt_hi, Zt_lo, MD_, scal, 0.f, nullptr, ME_SOFT2, stream);

    // 6. FISTA: beta_k precomputed in f32 exactly as the reference t-recurrence
    float t = 1.f;
    for (int k = 0; k < FITER; ++k) {
        float tn = (1.0f + sqrtf(1.0f + (4.0f * t) * t)) / 2.0f;
        float beta = (t - 1.0f) / tn;
        t = tn;
        // R = W @ Z - Y  (A = fp32 W split on the fly); rsq[k] += ||R||^2; Rt = split(R^T)
        launch_mgemm(nullptr, nullptr, Wd, NN_, Zt_hi, Zt_lo, 2816, NF_, MD_, NN_,
                     nullptr, x, Rt_hi, Rt_lo, KPAD, scal, 0.f, scal + 5 + k, ME_RESID, stream);
        // U = W^T R ; Gamma = soft(Z - eta U, thr); Zt <- Z_new (last iter: Zt <- Gamma for x_dec)
        launch_mgemm(Wt_hi, Wt_lo, nullptr, 0, Rt_hi, Rt_lo, MD_, NF_, KPAD, MD_,
                     Gamma, nullptr, Zt_hi, Zt_lo, MD_, scal, beta, nullptr,
                     (k == FITER - 1) ? ME_FISTA_G : ME_FISTA, stream);
    }

    // 7. x_dec = W @ Gamma (Zt now holds split Gamma)
    launch_mgemm(nullptr, nullptr, Wd, NN_, Zt_hi, Zt_lo, 2816, NF_, MD_, NN_,
                 x_dec, nullptr, nullptr, nullptr, 0, scal, 0.f, nullptr, ME_STORE, stream);
    // 8. tail GCN in fp32
    launch_gemm32(x_dec, gc1_w, NN_, NH_, NF_, xw, nullptr, EPI_NONE, stream);
    launch_gemm32(adj, xw, NN_, NH_, NN_, hbuf, gc1_b, EPI_BIASRELU, stream);
    launch_gemm32(hbuf, gc2_w, NN_, NC_, NH_, hw, nullptr, EPI_NONE, stream);
    launch_gemm32(adj, hw, NN_, NC_, NN_, obuf, gc2_b, EPI_BIAS, stream);
    // 9. log_softmax rows -> out0 ; norms -> out3
    logsoftmax_kernel<<<(NN_ + 3) / 4, 256, 0, stream>>>(obuf, logp);
    norms_kernel<<<1, 32, 0, stream>>>(scal, norms_o);
}

// Round 4
// 5857.038 us; speedup vs baseline: 6.3895x; 2.6061x over previous
//
#include <hip/hip_runtime.h>
#include <hip/hip_cooperative_groups.h>
#include <cstdint>
#include <cmath>

namespace cg = cooperative_groups;

#define NN_ 2708
#define NF_ 4096
#define MD_ 2048
#define NH_ 1024
#define NC_ 64
#define FITER 20
#define KPAD 2720   // 2708 padded to multiple of 32

// scal layout (floats in ws): [0]=c [1]=eta [2]=thr(lam/c) [3]=lam [4]=ynormsq [5..24]=rsq[k]

typedef _Float16 half8_t __attribute__((ext_vector_type(8)));
typedef _Float16 half4_t __attribute__((ext_vector_type(4)));
typedef float floatx4_t __attribute__((ext_vector_type(4)));

__device__ __forceinline__ float softt(float v, float t) {
    float a = fabsf(v) - t;
    a = a > 0.f ? a : 0.f;
    return copysignf(a, v);
}

__device__ __forceinline__ float blockReduceSum(float v, float* red) {
    int lane = threadIdx.x & 63, wid = threadIdx.x >> 6;
    #pragma unroll
    for (int off = 32; off; off >>= 1) v += __shfl_down(v, off);
    if (lane == 0) red[wid] = v;
    __syncthreads();
    if (wid == 0) {
        int nw = (blockDim.x + 63) >> 6;
        float r = (lane < nw) ? red[lane] : 0.f;
        #pragma unroll
        for (int off = 2; off; off >>= 1) r += __shfl_down(r, off);
        if (lane == 0) red[0] = r;
    }
    __syncthreads();
    float out = red[0];
    __syncthreads();
    return out;
}

// ---------- threefry2x32 + JAX normal init ----------
__device__ __forceinline__ float erfinv_f(float x) {
    float w = -log1pf(-x * x);
    float p;
    if (w < 5.0f) {
        w -= 2.5f;
        p = 2.81022636e-08f;
        p = fmaf(p, w, 3.43273939e-07f);
        p = fmaf(p, w, -3.5233877e-06f);
        p = fmaf(p, w, -4.39150654e-06f);
        p = fmaf(p, w, 0.00021858087f);
        p = fmaf(p, w, -0.00125372503f);
        p = fmaf(p, w, -0.00417768164f);
        p = fmaf(p, w, 0.246640727f);
        p = fmaf(p, w, 1.50140941f);
    } else {
        w = sqrtf(w) - 3.0f;
        p = -0.000200214257f;
        p = fmaf(p, w, 0.000100950558f);
        p = fmaf(p, w, 0.00134934322f);
        p = fmaf(p, w, -0.00367342844f);
        p = fmaf(p, w, 0.00573950773f);
        p = fmaf(p, w, -0.0076224613f);
        p = fmaf(p, w, 0.00943887047f);
        p = fmaf(p, w, 1.00167406f);
        p = fmaf(p, w, 2.83297682f);
    }
    return p * x;
}

__device__ __forceinline__ float u32_to_normal(uint32_t bits) {
    uint32_t fb = (bits >> 9) | 0x3F800000u;
    float f = __uint_as_float(fb) - 1.0f;        // [0,1)
    const float lo = -0.99999994f;               // nextafter(-1,0) in f32
    float u = fmaf(f, 2.0f, lo);
    u = fmaxf(lo, u);
    return 1.41421356f * erfinv_f(u);
}

__global__ void init_x0_kernel(float* __restrict__ X0) {
    int i = blockIdx.x * blockDim.x + threadIdx.x;   // 0..1023 pairs
    if (i >= MD_ / 2) return;
    uint32_t x0 = (uint32_t)i, x1 = (uint32_t)(i + MD_ / 2);
    const uint32_t k0 = 0u, k1 = 1u, k2 = 0x1BD11BDBu;
    const uint32_t ks[3] = {k0, k1, k2};
    x0 += k0; x1 += k1;
    const int rot[8] = {13, 15, 26, 6, 17, 29, 16, 24};
    #pragma unroll
    for (int g = 0; g < 5; ++g) {
        const int base = (g & 1) ? 4 : 0;
        #pragma unroll
        for (int rr = 0; rr < 4; ++rr) {
            x0 += x1;
            int r = rot[base + rr];
            x1 = (x1 << r) | (x1 >> (32 - r));
            x1 ^= x0;
        }
        x0 += ks[(g + 1) % 3];
        x1 += ks[(g + 2) % 3] + (uint32_t)(g + 1);
    }
    X0[i] = u32_to_normal(x0);
    X0[i + MD_ / 2] = u32_to_normal(x1);
}

__global__ void zero_scal_kernel(float* __restrict__ scal) {
    int t = threadIdx.x;
    if (t < 32) scal[t] = 0.f;
}

__global__ void fill0_kernel(uint32_t* __restrict__ p, int n32) {
    int i = blockIdx.x * blockDim.x + threadIdx.x;
    if (i < n32) p[i] = 0u;
}

__global__ void sumsq_kernel(const float* __restrict__ X, int n, float* __restrict__ acc) {
    __shared__ float red[8];
    float s = 0.f;
    for (size_t i = (size_t)blockIdx.x * blockDim.x + threadIdx.x; i < (size_t)n;
         i += (size_t)gridDim.x * blockDim.x) {
        float v = X[i];
        s += v * v;
    }
    s = blockReduceSum(s, red);
    if (threadIdx.x == 0) atomicAdd(acc, s);
}

// ---------- transpose + split fp32 -> f16 hi/lo, out[c][r] padded to Rpad ----------
__global__ void tsplit_kernel(const float* __restrict__ src, int R, int ld, int Rpad,
                              _Float16* __restrict__ hi, _Float16* __restrict__ lo) {
    __shared__ float t[32][33];
    int rb = blockIdx.y * 32, cb = blockIdx.x * 32;
    int tx = threadIdx.x & 31, ty = threadIdx.x >> 5;   // ty 0..7
    #pragma unroll
    for (int s = 0; s < 32; s += 8) {
        int r = rb + ty + s, c = cb + tx;
        t[ty + s][tx] = (r < R) ? src[(size_t)r * ld + c] : 0.f;
    }
    __syncthreads();
    #pragma unroll
    for (int s = 0; s < 32; s += 8) {
        int c = cb + ty + s, r = rb + tx;
        float v = t[tx][ty + s];
        _Float16 h = (_Float16)v;
        size_t o = (size_t)c * Rpad + r;
        hi[o] = h;
        lo[o] = (_Float16)(v - (float)h);
    }
}

// ---------- adj -> split f16 hi/lo, [2816][2720] zero-padded, non-transposed ----------
__global__ void splitadj_kernel(const float* __restrict__ adj,
                                _Float16* __restrict__ hi, _Float16* __restrict__ lo) {
    int r = blockIdx.x;   // 0..2815
    for (int c = threadIdx.x; c < KPAD; c += 256) {
        float v = (r < NN_ && c < NN_) ? adj[(size_t)r * NN_ + c] : 0.f;
        _Float16 h = (_Float16)v;
        size_t o = (size_t)r * KPAD + c;
        hi[o] = h;
        lo[o] = (_Float16)(v - (float)h);
    }
}

// ---------- Gamma0 = soft(eta*B, lam); Zt = split(Gamma0^T) ----------
__global__ void g0_kernel(const float* __restrict__ Bm, const float* __restrict__ scal,
                          float* __restrict__ Gamma,
                          _Float16* __restrict__ Zh, _Float16* __restrict__ Zl) {
    __shared__ float t[32][33];
    int rb = blockIdx.y * 32;   // m-dim (2048)
    int cb = blockIdx.x * 32;   // nfeat (4096)
    float eta = scal[1], lam = scal[3];
    int tx = threadIdx.x & 31, ty = threadIdx.x >> 5;
    #pragma unroll
    for (int s = 0; s < 32; s += 8) {
        int r = rb + ty + s, c = cb + tx;
        float g = softt(eta * Bm[(size_t)r * NF_ + c], lam);
        Gamma[(size_t)r * NF_ + c] = g;
        t[ty + s][tx] = g;
    }
    __syncthreads();
    #pragma unroll
    for (int s = 0; s < 32; s += 8) {
        int c = cb + ty + s, r = rb + tx;
        float v = t[tx][ty + s];
        _Float16 h = (_Float16)v;
        size_t o = (size_t)c * MD_ + r;
        Zh[o] = h;
        Zl[o] = (_Float16)(v - (float)h);
    }
}

// ---------- cooperative power method: 48x G^2, then 4x G (exactly 100 applies) ----------
#define P2ITER 52
__global__ __launch_bounds__(256)
void power2_kernel(const float* __restrict__ G2, const _Float16* __restrict__ Gh,
                   const _Float16* __restrict__ Gl, const int* __restrict__ Kp,
                   float* __restrict__ scal, float* __restrict__ Xa, float* __restrict__ Xb) {
    cg::grid_group grid = cg::this_grid();
    __shared__ float xs[MD_];
    __shared__ float red[8];
    const int tid = threadIdx.x, bid = blockIdx.x;
    const int w = tid >> 6, l = tid & 63;
    const int r0 = bid * 8;    // 256 blocks x 8 rows = 2048

    for (int it = 0; it < P2ITER; ++it) {
        const float* Xc = (it & 1) ? Xb : Xa;
        float* Xn = (it & 1) ? Xa : Xb;
        float ss = 0.f;
        for (int k = tid; k < MD_; k += 256) { float v = Xc[k]; xs[k] = v; ss += v * v; }
        __syncthreads();
        ss = blockReduceSum(ss, red);
        float inv = 1.0f / sqrtf(ss);
        #pragma unroll
        for (int rr = 0; rr < 2; ++rr) {
            int r = r0 + w * 2 + rr;
            float s = 0.f;
            if (it < P2ITER - 4) {
                const float* Gr = G2 + (size_t)r * MD_;
                #pragma unroll
                for (int q = 0; q < 8; ++q) {
                    int o = (q * 64 + l) * 4;
                    float4 g = *reinterpret_cast<const float4*>(Gr + o);
                    float4 xv = *reinterpret_cast<const float4*>(&xs[o]);
                    s = fmaf(g.x, xv.x, s); s = fmaf(g.y, xv.y, s);
                    s = fmaf(g.z, xv.z, s); s = fmaf(g.w, xv.w, s);
                }
            } else {
                const _Float16* ghr = Gh + (size_t)r * MD_;
                const _Float16* glr = Gl + (size_t)r * MD_;
                #pragma unroll
                for (int q = 0; q < 8; ++q) {
                    int o = (q * 64 + l) * 4;
                    half4_t hv = *reinterpret_cast<const half4_t*>(ghr + o);
                    half4_t lv = *reinterpret_cast<const half4_t*>(glr + o);
                    float4 xv = *reinterpret_cast<const float4*>(&xs[o]);
                    s = fmaf((float)hv[0] + (float)lv[0], xv.x, s);
                    s = fmaf((float)hv[1] + (float)lv[1], xv.y, s);
                    s = fmaf((float)hv[2] + (float)lv[2], xv.z, s);
                    s = fmaf((float)hv[3] + (float)lv[3], xv.w, s);
                }
            }
            #pragma unroll
            for (int off = 32; off; off >>= 1) s += __shfl_down(s, off);
            if (l == 0) Xn[r] = s * inv;
        }
        grid.sync();
    }
    if (bid == 0) {
        const float* Xf = ((P2ITER - 1) & 1) ? Xa : Xb;
        float ss = 0.f;
        for (int k = tid; k < MD_; k += 256) { float v = Xf[k]; ss += v * v; }
        ss = blockReduceSum(ss, red);
        if (tid == 0) {
            float c = sqrtf(ss);
            float lam = (float)Kp[0];
            scal[0] = c;
            scal[1] = 1.0f / c;
            scal[2] = lam / c;
            scal[3] = lam;
        }
    }
}

// ---------- split-f16 MFMA GEMM (3-product), 128x128 tile, BK=32 ----------
enum { ME_STORE = 0, ME_SYMSPLIT = 1, ME_SPLIT_T = 2, ME_FISTAG = 3, ME_FISTAG_LAST = 4,
       ME_BIAS = 5, ME_BIASRELU = 6 };

__device__ __forceinline__ void stage_h(const _Float16* __restrict__ g, int row0, int K, int kk,
                                        _Float16* s, int w, int l) {
    #pragma unroll
    for (int p = 0; p < 2; ++p) {
        int c = p * 256 + w * 64 + l;                       // chunk id, lanes contiguous
        const _Float16* gp = g + (size_t)(row0 + (c >> 2)) * K + kk + ((c & 3) << 3);
        _Float16* lp = s + ((size_t)(p * 256 + w * 64) << 3);   // wave-uniform base
        __builtin_amdgcn_global_load_lds(
            (const __attribute__((address_space(1))) void*)gp,
            (__attribute__((address_space(3))) void*)lp, 16, 0, 0);
    }
}

template <bool AFP32>
__global__ __launch_bounds__(256)
void mgemm_kernel(const _Float16* __restrict__ Ah, const _Float16* __restrict__ Al,
                  const float* __restrict__ Afp, int Marr,
                  const _Float16* __restrict__ Bh, const _Float16* __restrict__ Bl,
                  int K, int Mvalid, int Nvalid, int ldc,
                  float* __restrict__ C, const float* __restrict__ BmP,
                  const float* __restrict__ bias,
                  _Float16* __restrict__ Th, _Float16* __restrict__ Tl, int Tstride,
                  const float* __restrict__ scal, float betak,
                  float* __restrict__ nrm_acc, int epi) {
    __shared__ __align__(16) _Float16 sAh[128 * 32], sAl[128 * 32];
    __shared__ __align__(16) _Float16 sBh[128 * 32], sBl[128 * 32];
    __shared__ float red[8];
    const int tid = threadIdx.x;
    const int w = tid >> 6, l = tid & 63;
    const int wr = w >> 1, wc = w & 1;
    const int quad = l >> 4, lc = l & 15;
    const int row0 = blockIdx.y * 128, col0 = blockIdx.x * 128;

    floatx4_t acc[4][4];
    #pragma unroll
    for (int i = 0; i < 4; ++i)
        #pragma unroll
        for (int j = 0; j < 4; ++j) {
            floatx4_t z = {0.f, 0.f, 0.f, 0.f};
            acc[i][j] = z;
        }

    for (int kk = 0; kk < K; kk += 32) {
        if constexpr (AFP32) {
            #pragma unroll
            for (int p = 0; p < 4; ++p) {
                int c2 = p * 256 + tid;                 // 0..1023
                int r = c2 >> 3, k4 = (c2 & 7) << 2;
                int gr = row0 + r;
                gr = gr < Marr ? gr : Marr - 1;         // clamp; masked at store
                float4 v = *reinterpret_cast<const float4*>(Afp + (size_t)gr * K + kk + k4);
                half4_t hh, ll;
                hh[0] = (_Float16)v.x; ll[0] = (_Float16)(v.x - (float)hh[0]);
                hh[1] = (_Float16)v.y; ll[1] = (_Float16)(v.y - (float)hh[1]);
                hh[2] = (_Float16)v.z; ll[2] = (_Float16)(v.z - (float)hh[2]);
                hh[3] = (_Float16)v.w; ll[3] = (_Float16)(v.w - (float)hh[3]);
                *reinterpret_cast<half4_t*>(&sAh[r * 32 + k4]) = hh;
                *reinterpret_cast<half4_t*>(&sAl[r * 32 + k4]) = ll;
            }
        } else {
            stage_h(Ah, row0, K, kk, sAh, w, l);
            stage_h(Al, row0, K, kk, sAl, w, l);
        }
        stage_h(Bh, col0, K, kk, sBh, w, l);
        stage_h(Bl, col0, K, kk, sBl, w, l);
        asm volatile("s_waitcnt vmcnt(0)" ::: "memory");
        __syncthreads();

        half8_t fAh[4], fAl[4], fBh[4], fBl[4];
        #pragma unroll
        for (int i = 0; i < 4; ++i) {
            int oa = (wr * 64 + i * 16 + lc) * 32 + quad * 8;
            fAh[i] = *reinterpret_cast<const half8_t*>(&sAh[oa]);
            fAl[i] = *reinterpret_cast<const half8_t*>(&sAl[oa]);
            int ob = (wc * 64 + i * 16 + lc) * 32 + quad * 8;
            fBh[i] = *reinterpret_cast<const half8_t*>(&sBh[ob]);
            fBl[i] = *reinterpret_cast<const half8_t*>(&sBl[ob]);
        }
        #pragma unroll
        for (int i = 0; i < 4; ++i)
            #pragma unroll
            for (int j = 0; j < 4; ++j) {
                acc[i][j] = __builtin_amdgcn_mfma_f32_16x16x32_f16(fAh[i], fBh[j], acc[i][j], 0, 0, 0);
                acc[i][j] = __builtin_amdgcn_mfma_f32_16x16x32_f16(fAh[i], fBl[j], acc[i][j], 0, 0, 0);
                acc[i][j] = __builtin_amdgcn_mfma_f32_16x16x32_f16(fAl[i], fBh[j], acc[i][j], 0, 0, 0);
            }
        __syncthreads();
    }

    float eta = 0.f, thr = 0.f;
    if (epi == ME_FISTAG || epi == ME_FISTAG_LAST) { eta = scal[1]; thr = scal[2]; }
    float rsq = 0.f;
    #pragma unroll
    for (int i = 0; i < 4; ++i) {
        int grow0 = row0 + wr * 64 + i * 16 + quad * 4;
        bool rowok = grow0 < Mvalid;
        #pragma unroll
        for (int j = 0; j < 4; ++j) {
            int gcol = col0 + wc * 64 + j * 16 + lc;
            bool colok = gcol < Nvalid;
            floatx4_t v = acc[i][j];
            if (epi == ME_STORE) {
                if (rowok && colok) {
                    #pragma unroll
                    for (int r = 0; r < 4; ++r) C[(size_t)(grow0 + r) * ldc + gcol] = v[r];
                }
            } else if (epi == ME_SYMSPLIT) {
                #pragma unroll
                for (int r = 0; r < 4; ++r) {
                    _Float16 h = (_Float16)v[r];
                    size_t o = (size_t)(grow0 + r) * Tstride + gcol;
                    Th[o] = h;
                    Tl[o] = (_Float16)(v[r] - (float)h);
                }
            } else if (epi == ME_SPLIT_T) {
                if (rowok && colok) {
                    half4_t hh, ll;
                    #pragma unroll
                    for (int r = 0; r < 4; ++r) {
                        _Float16 h = (_Float16)v[r];
                        hh[r] = h; ll[r] = (_Float16)(v[r] - (float)h);
                    }
                    size_t to = (size_t)gcol * Tstride + grow0;
                    *reinterpret_cast<half4_t*>(&Th[to]) = hh;
                    *reinterpret_cast<half4_t*>(&Tl[to]) = ll;
                }
            } else if (epi == ME_FISTAG || epi == ME_FISTAG_LAST) {
                // Z_in read from Bh/Bl (same buffer as B operand), Z_out -> Th/Tl
                // (physically distinct buffers: ping-pong; no intra-launch hazard)
                size_t to = (size_t)gcol * Tstride + grow0;
                half4_t zh = *reinterpret_cast<const half4_t*>(&Bh[to]);
                half4_t zl = *reinterpret_cast<const half4_t*>(&Bl[to]);
                half4_t oh, ol;
                #pragma unroll
                for (int r = 0; r < 4; ++r) {
                    float z = (float)zh[r] + (float)zl[r];
                    float p = v[r];
                    float bi = BmP[(size_t)(grow0 + r) * NF_ + gcol];
                    rsq = fmaf(z, p - 2.0f * bi, rsq);          // <Z,GZ> - 2<Z,B>
                    float g = z - eta * (p - bi);
                    float gn = softt(g, thr);
                    size_t ci = (size_t)(grow0 + r) * NF_ + gcol;
                    float gold = C[ci];
                    C[ci] = gn;
                    float zo = (epi == ME_FISTAG) ? (gn + betak * (gn - gold)) : gn;
                    _Float16 h = (_Float16)zo;
                    oh[r] = h; ol[r] = (_Float16)(zo - (float)h);
                }
                *reinterpret_cast<half4_t*>(&Th[to]) = oh;
                *reinterpret_cast<half4_t*>(&Tl[to]) = ol;
            } else {   // ME_BIAS / ME_BIASRELU
                if (rowok && colok) {
                    #pragma unroll
                    for (int r = 0; r < 4; ++r) {
                        float s = v[r] + bias[gcol];
                        if (epi == ME_BIASRELU) s = s > 0.f ? s : 0.f;
                        C[(size_t)(grow0 + r) * ldc + gcol] = s;
                    }
                }
            }
        }
    }
    if (epi == ME_FISTAG || epi == ME_FISTAG_LAST) {
        float tot = blockReduceSum(rsq, red);
        if (tid == 0) atomicAdd(nrm_acc, tot);
    }
}

__global__ void logsoftmax_kernel(const float* __restrict__ O, float* __restrict__ out) {
    int row = blockIdx.x * 4 + (threadIdx.x >> 6);
    int lane = threadIdx.x & 63;
    if (row >= NN_) return;
    float v = O[row * NC_ + lane];
    float m = v;
    #pragma unroll
    for (int off = 32; off; off >>= 1) m = fmaxf(m, __shfl_xor(m, off));
    float e = expf(v - m);
    float s = e;
    #pragma unroll
    for (int off = 32; off; off >>= 1) s += __shfl_xor(s, off);
    out[row * NC_ + lane] = (v - m) - logf(s);
}

__global__ void norms_kernel(const float* __restrict__ scal, float* __restrict__ nout) {
    int k = threadIdx.x;
    if (k < FITER) {
        float ysq = scal[4];
        float v = scal[5 + k] + ysq;            // ||WZ-Y||^2 via Gram identity
        nout[k] = sqrtf(fmaxf(v, 0.f)) / sqrtf(ysq);
    }
}

static inline void launch_m(bool afp32, dim3 grid,
                            const _Float16* Ah, const _Float16* Al,
                            const float* Afp, int Marr,
                            const _Float16* Bh, const _Float16* Bl,
                            int K, int Mvalid, int Nvalid, int ldc,
                            float* C, const float* BmP, const float* bias,
                            _Float16* Th, _Float16* Tl, int Tstride,
                            const float* scal, float betak, float* nrm, int epi,
                            hipStream_t s) {
    if (afp32)
        mgemm_kernel<true><<<grid, dim3(256), 0, s>>>(
            Ah, Al, Afp, Marr, Bh, Bl, K, Mvalid, Nvalid, ldc, C, BmP, bias,
            Th, Tl, Tstride, scal, betak, nrm, epi);
    else
        mgemm_kernel<false><<<grid, dim3(256), 0, s>>>(
            Ah, Al, Afp, Marr, Bh, Bl, K, Mvalid, Nvalid, ldc, C, BmP, bias,
            Th, Tl, Tstride, scal, betak, nrm, epi);
}

extern "C" void kernel_launch(void* const* d_in, const int* in_sizes, int n_in,
                              void* d_out, int out_size, void* d_ws, size_t ws_size,
                              hipStream_t stream) {
    const float* x     = (const float*)d_in[0];   // (2708, 4096)
    const float* adj   = (const float*)d_in[1];   // (2708, 2708)
    const float* gc1_w = (const float*)d_in[2];   // (4096, 1024)
    const float* gc1_b = (const float*)d_in[3];   // (1024,)
    const float* gc2_w = (const float*)d_in[4];   // (1024, 64)
    const float* gc2_b = (const float*)d_in[5];   // (64,)
    const float* Wd    = (const float*)d_in[6];   // (2708, 2048)
    const int*   Kp    = (const int*)d_in[7];     // scalar K

    float* out = (float*)d_out;
    float* logp    = out;                                     // (2708, 64)
    float* x_dec   = logp + (size_t)NN_ * NC_;                // (2708, 4096)
    float* Gamma   = x_dec + (size_t)NN_ * NF_;               // (2048, 4096)
    float* norms_o = Gamma + (size_t)MD_ * NF_;               // (20,)

    // ---- ws layout: 100,679,808 B (same proven footprint) ----
    char* wsb = (char*)d_ws;
    const size_t OFF_R1 = 16512;                       // after scal/Xa/Xb
    const size_t OFF_R2 = OFF_R1 + 16777216;           // Gh/Gl (16.78 MB)
    const size_t OFF_R3 = OFF_R2 + 33554432;           // Bm (33.55 MB)
    const size_t OFF_R4 = OFF_R3 + 33554432;           // Wt+xth_hi -> ZtA (33.55 MB)
    float* scal = (float*)wsb;
    float* Xa   = scal + 32;
    float* Xb   = Xa + MD_;
    _Float16* Gh = (_Float16*)(wsb + OFF_R1);
    _Float16* Gl = Gh + (size_t)MD_ * MD_;
    float* Bm = (float*)(wsb + OFF_R2);
    // R3 phase 1: Wt + xth_hi
    _Float16* Wt_hi  = (_Float16*)(wsb + OFF_R3);
    _Float16* Wt_lo  = Wt_hi + (size_t)MD_ * KPAD;
    _Float16* xth_hi = Wt_lo + (size_t)MD_ * KPAD;     // 11.14 MB, fits slack
    _Float16* xth_lo = (_Float16*)(wsb + OFF_R4);      // R4 phase 1
    // R3 phase 2: ZtA (4096 x 2048 split, ping)
    _Float16* ZA_hi = (_Float16*)(wsb + OFF_R3);
    _Float16* ZA_lo = ZA_hi + (size_t)NF_ * MD_;
    // pong: the x_dec slab of d_out (44.4 MB >= 33.55 MB), scratch until phase 3
    _Float16* ZB_hi = (_Float16*)x_dec;
    _Float16* ZB_lo = ZB_hi + (size_t)NF_ * MD_;
    float* G2 = (float*)(wsb + OFF_R4);                // R4 phase 2 (16.78 MB)
    // R2 phase 3: adj split [2816][2720]
    _Float16* adjT_hi = (_Float16*)(wsb + OFF_R2);
    _Float16* adjT_lo = adjT_hi + (size_t)2816 * KPAD;
    // R1 phase 3: gc1^T split [1024][4096]
    _Float16* g1t_hi = (_Float16*)(wsb + OFF_R1);
    _Float16* g1t_lo = g1t_hi + (size_t)NH_ * NF_;
    // R3 phase 3
    _Float16* xwT_hi = (_Float16*)(wsb + OFF_R3);                  // [1024][2720]
    _Float16* xwT_lo = xwT_hi + (size_t)NH_ * KPAD;
    float*    hbuf   = (float*)(wsb + OFF_R3 + 11141120);          // [2708][1024]
    _Float16* hwT_hi = (_Float16*)(wsb + OFF_R3 + 22233088);       // [128][2720]
    _Float16* hwT_lo = hwT_hi + (size_t)128 * KPAD;
    _Float16* g2t_hi = (_Float16*)(wsb + OFF_R3 + 23625728);       // [128][1024]
    _Float16* g2t_lo = g2t_hi + (size_t)128 * NH_;
    float*    obuf   = (float*)(wsb + OFF_R3 + 24150016);          // [2708][64]

    const _Float16* nullh = nullptr;

    // ---- phase 1: init, Gram matrix, B = W^T Y, G^2, power, Gamma0 ----
    zero_scal_kernel<<<1, 64, 0, stream>>>(scal);
    init_x0_kernel<<<4, 256, 0, stream>>>(Xa);
    sumsq_kernel<<<1024, 256, 0, stream>>>(x, NN_ * NF_, scal + 4);

    tsplit_kernel<<<dim3(MD_ / 32, KPAD / 32), 256, 0, stream>>>(Wd, NN_, MD_, KPAD, Wt_hi, Wt_lo);
    // G = W^T W (split-sym output only)
    launch_m(false, dim3(16, 16), Wt_hi, Wt_lo, nullptr, 0, Wt_hi, Wt_lo,
             KPAD, MD_, MD_, 0, nullptr, nullptr, nullptr, Gh, Gl, MD_,
             scal, 0.f, nullptr, ME_SYMSPLIT, stream);
    // B = W^T Y in two N-halves (xth buffer reused)
    for (int half = 0; half < 2; ++half) {
        tsplit_kernel<<<dim3(MD_ / 32, KPAD / 32), 256, 0, stream>>>(
            x + half * 2048, NN_, NF_, KPAD, xth_hi, xth_lo);
        launch_m(false, dim3(16, 16), Wt_hi, Wt_lo, nullptr, 0, xth_hi, xth_lo,
                 KPAD, MD_, MD_, NF_, Bm + half * 2048, nullptr, nullptr,
                 nullptr, nullptr, 0, scal, 0.f, nullptr, ME_STORE, stream);
    }
    // G2 = G @ G  (G symmetric -> same split buffer both sides)
    launch_m(false, dim3(16, 16), Gh, Gl, nullptr, 0, Gh, Gl,
             MD_, MD_, MD_, MD_, G2, nullptr, nullptr,
             nullptr, nullptr, 0, scal, 0.f, nullptr, ME_STORE, stream);
    // cooperative power method (proven pattern: non-template kernel, 1 block/CU)
    {
        void* args[] = {(void*)&G2, (void*)&Gh, (void*)&Gl, (void*)&Kp,
                        (void*)&scal, (void*)&Xa, (void*)&Xb};
        hipLaunchCooperativeKernel((void*)power2_kernel, dim3(256), dim3(256), args, 0, stream);
    }
    // Gamma0 = soft(eta*B, lam); ZtA = split(Gamma0^T)
    g0_kernel<<<dim3(NF_ / 32, MD_ / 32), 256, 0, stream>>>(Bm, scal, Gamma, ZA_hi, ZA_lo);

    // ---- phase 2: FISTA in Gram domain, Z ping-pong (plain launches, race-free) ----
    {
        float t = 1.f;
        for (int k = 0; k < FITER; ++k) {
            float tn = (1.0f + sqrtf(1.0f + (4.0f * t) * t)) / 2.0f;
            float beta = (t - 1.0f) / tn;
            t = tn;
            _Float16* in_hi  = (k & 1) ? ZB_hi : ZA_hi;
            _Float16* in_lo  = (k & 1) ? ZB_lo : ZA_lo;
            _Float16* out_hi = (k & 1) ? ZA_hi : ZB_hi;
            _Float16* out_lo = (k & 1) ? ZA_lo : ZB_lo;
            launch_m(false, dim3(32, 16), Gh, Gl, nullptr, 0, in_hi, in_lo,
                     MD_, MD_, NF_, NF_, Gamma, Bm, nullptr,
                     out_hi, out_lo, MD_, scal, beta, scal + 5 + k,
                     (k == FITER - 1) ? ME_FISTAG_LAST : ME_FISTAG, stream);
        }
        // FITER=20 even: final Gamma-split lands in ZA (ws); ZB (x_dec slab) is dead
    }

    // ---- phase 3: decode + GCN tail (all MFMA) ----
    splitadj_kernel<<<2816, 256, 0, stream>>>(adj, adjT_hi, adjT_lo);
    // x_dec = W @ Gamma  (ZA holds split Gamma^T; output overwrites the dead ZB slab)
    launch_m(true, dim3(32, 22), nullh, nullh, Wd, NN_, ZA_hi, ZA_lo,
             MD_, NN_, NF_, NF_, x_dec, nullptr, nullptr,
             nullptr, nullptr, 0, scal, 0.f, nullptr, ME_STORE, stream);
    tsplit_kernel<<<dim3(NH_ / 32, NF_ / 32), 256, 0, stream>>>(gc1_w, NF_, NH_, NF_, g1t_hi, g1t_lo);
    fill0_kernel<<<(2785280 + 255) / 256, 256, 0, stream>>>((uint32_t*)xwT_hi, 2785280);
    // xw^T = split((x_dec @ gc1_w)^T)
    launch_m(true, dim3(8, 22), nullh, nullh, x_dec, NN_, g1t_hi, g1t_lo,
             NF_, NN_, NH_, 0, nullptr, nullptr, nullptr,
             xwT_hi, xwT_lo, KPAD, scal, 0.f, nullptr, ME_SPLIT_T, stream);
    // h = relu(adj @ xw + b1)
    launch_m(false, dim3(8, 22), adjT_hi, adjT_lo, nullptr, 0, xwT_hi, xwT_lo,
             KPAD, NN_, NH_, NH_, hbuf, nullptr, gc1_b,
             nullptr, nullptr, 0, scal, 0.f, nullptr, ME_BIASRELU, stream);
    fill0_kernel<<<(131072 + 255) / 256, 256, 0, stream>>>((uint32_t*)g2t_hi, 131072);
    tsplit_kernel<<<dim3(NC_ / 32, NH_ / 32), 256, 0, stream>>>(gc2_w, NH_, NC_, NH_, g2t_hi, g2t_lo);
    fill0_kernel<<<(348160 + 255) / 256, 256, 0, stream>>>((uint32_t*)hwT_hi, 348160);
    // hw^T = split((h @ gc2_w)^T)
    launch_m(true, dim3(1, 22), nullh, nullh, hbuf, NN_, g2t_hi, g2t_lo,
             NH_, NN_, NC_, 0, nullptr, nullptr, nullptr,
             hwT_hi, hwT_lo, KPAD, scal, 0.f, nullptr, ME_SPLIT_T, stream);
    // o = adj @ hw + b2
    launch_m(false, dim3(1, 22), adjT_hi, adjT_lo, nullptr, 0, hwT_hi, hwT_lo,
             KPAD, NN_, NC_, NC_, obuf, nullptr, gc2_b,
             nullptr, nullptr, 0, scal, 0.f, nullptr, ME_BIAS, stream);
    logsoftmax_kernel<<<(NN_ + 3) / 4, 256, 0, stream>>>(obuf, logp);
    norms_kernel<<<1, 32, 0, stream>>>(scal, norms_o);
}

// Round 5
// 4494.441 us; speedup vs baseline: 8.3266x; 1.3032x over previous
//
#include <hip/hip_runtime.h>
#include <hip/hip_cooperative_groups.h>
#include <cstdint>
#include <cmath>

namespace cg = cooperative_groups;

#define NN_ 2708
#define NF_ 4096
#define MD_ 2048
#define NH_ 1024
#define NC_ 64
#define FITER 20
#define KPAD 2720   // 2708 padded to multiple of 32

// scal layout (floats in ws): [0]=c [1]=eta [2]=thr(lam/c) [3]=lam [4]=ynormsq [5..24]=rsq[k]

typedef _Float16 half8_t __attribute__((ext_vector_type(8)));
typedef _Float16 half4_t __attribute__((ext_vector_type(4)));
typedef float floatx4_t __attribute__((ext_vector_type(4)));

__device__ __forceinline__ float softt(float v, float t) {
    float a = fabsf(v) - t;
    a = a > 0.f ? a : 0.f;
    return copysignf(a, v);
}

__device__ __forceinline__ float blockReduceSum(float v, float* red) {
    int lane = threadIdx.x & 63, wid = threadIdx.x >> 6;
    #pragma unroll
    for (int off = 32; off; off >>= 1) v += __shfl_down(v, off);
    if (lane == 0) red[wid] = v;
    __syncthreads();
    if (wid == 0) {
        int nw = (blockDim.x + 63) >> 6;
        float r = (lane < nw) ? red[lane] : 0.f;
        #pragma unroll
        for (int off = 2; off; off >>= 1) r += __shfl_down(r, off);
        if (lane == 0) red[0] = r;
    }
    __syncthreads();
    float out = red[0];
    __syncthreads();
    return out;
}

// ---------- threefry2x32 + JAX normal init ----------
__device__ __forceinline__ float erfinv_f(float x) {
    float w = -log1pf(-x * x);
    float p;
    if (w < 5.0f) {
        w -= 2.5f;
        p = 2.81022636e-08f;
        p = fmaf(p, w, 3.43273939e-07f);
        p = fmaf(p, w, -3.5233877e-06f);
        p = fmaf(p, w, -4.39150654e-06f);
        p = fmaf(p, w, 0.00021858087f);
        p = fmaf(p, w, -0.00125372503f);
        p = fmaf(p, w, -0.00417768164f);
        p = fmaf(p, w, 0.246640727f);
        p = fmaf(p, w, 1.50140941f);
    } else {
        w = sqrtf(w) - 3.0f;
        p = -0.000200214257f;
        p = fmaf(p, w, 0.000100950558f);
        p = fmaf(p, w, 0.00134934322f);
        p = fmaf(p, w, -0.00367342844f);
        p = fmaf(p, w, 0.00573950773f);
        p = fmaf(p, w, -0.0076224613f);
        p = fmaf(p, w, 0.00943887047f);
        p = fmaf(p, w, 1.00167406f);
        p = fmaf(p, w, 2.83297682f);
    }
    return p * x;
}

__device__ __forceinline__ float u32_to_normal(uint32_t bits) {
    uint32_t fb = (bits >> 9) | 0x3F800000u;
    float f = __uint_as_float(fb) - 1.0f;        // [0,1)
    const float lo = -0.99999994f;               // nextafter(-1,0) in f32
    float u = fmaf(f, 2.0f, lo);
    u = fmaxf(lo, u);
    return 1.41421356f * erfinv_f(u);
}

__global__ void init_x0_kernel(float* __restrict__ X0) {
    int i = blockIdx.x * blockDim.x + threadIdx.x;   // 0..1023 pairs
    if (i >= MD_ / 2) return;
    uint32_t x0 = (uint32_t)i, x1 = (uint32_t)(i + MD_ / 2);
    const uint32_t k0 = 0u, k1 = 1u, k2 = 0x1BD11BDBu;
    const uint32_t ks[3] = {k0, k1, k2};
    x0 += k0; x1 += k1;
    const int rot[8] = {13, 15, 26, 6, 17, 29, 16, 24};
    #pragma unroll
    for (int g = 0; g < 5; ++g) {
        const int base = (g & 1) ? 4 : 0;
        #pragma unroll
        for (int rr = 0; rr < 4; ++rr) {
            x0 += x1;
            int r = rot[base + rr];
            x1 = (x1 << r) | (x1 >> (32 - r));
            x1 ^= x0;
        }
        x0 += ks[(g + 1) % 3];
        x1 += ks[(g + 2) % 3] + (uint32_t)(g + 1);
    }
    X0[i] = u32_to_normal(x0);
    X0[i + MD_ / 2] = u32_to_normal(x1);
}

__global__ void zero_scal_kernel(float* __restrict__ scal) {
    int t = threadIdx.x;
    if (t < 32) scal[t] = 0.f;
}

__global__ void fill0_kernel(uint32_t* __restrict__ p, int n32) {
    int i = blockIdx.x * blockDim.x + threadIdx.x;
    if (i < n32) p[i] = 0u;
}

__global__ void sumsq_kernel(const float* __restrict__ X, int n, float* __restrict__ acc) {
    __shared__ float red[8];
    float s = 0.f;
    for (size_t i = (size_t)blockIdx.x * blockDim.x + threadIdx.x; i < (size_t)n;
         i += (size_t)gridDim.x * blockDim.x) {
        float v = X[i];
        s += v * v;
    }
    s = blockReduceSum(s, red);
    if (threadIdx.x == 0) atomicAdd(acc, s);
}

// ---------- transpose + split fp32 -> f16 hi/lo, out[c][r] padded to Rpad ----------
__global__ void tsplit_kernel(const float* __restrict__ src, int R, int ld, int Rpad,
                              _Float16* __restrict__ hi, _Float16* __restrict__ lo) {
    __shared__ float t[32][33];
    int rb = blockIdx.y * 32, cb = blockIdx.x * 32;
    int tx = threadIdx.x & 31, ty = threadIdx.x >> 5;   // ty 0..7
    #pragma unroll
    for (int s = 0; s < 32; s += 8) {
        int r = rb + ty + s, c = cb + tx;
        t[ty + s][tx] = (r < R) ? src[(size_t)r * ld + c] : 0.f;
    }
    __syncthreads();
    #pragma unroll
    for (int s = 0; s < 32; s += 8) {
        int c = cb + ty + s, r = rb + tx;
        float v = t[tx][ty + s];
        _Float16 h = (_Float16)v;
        size_t o = (size_t)c * Rpad + r;
        hi[o] = h;
        lo[o] = (_Float16)(v - (float)h);
    }
}

// ---------- adj -> split f16 hi/lo, [2816][2720] zero-padded, non-transposed ----------
__global__ void splitadj_kernel(const float* __restrict__ adj,
                                _Float16* __restrict__ hi, _Float16* __restrict__ lo) {
    int r = blockIdx.x;   // 0..2815
    for (int c = threadIdx.x; c < KPAD; c += 256) {
        float v = (r < NN_ && c < NN_) ? adj[(size_t)r * NN_ + c] : 0.f;
        _Float16 h = (_Float16)v;
        size_t o = (size_t)r * KPAD + c;
        hi[o] = h;
        lo[o] = (_Float16)(v - (float)h);
    }
}

// ---------- Gamma0 = soft(eta*B, lam); Zt = split(Gamma0^T) ----------
__global__ void g0_kernel(const float* __restrict__ Bm, const float* __restrict__ scal,
                          float* __restrict__ Gamma,
                          _Float16* __restrict__ Zh, _Float16* __restrict__ Zl) {
    __shared__ float t[32][33];
    int rb = blockIdx.y * 32;   // m-dim (2048)
    int cb = blockIdx.x * 32;   // nfeat (4096)
    float eta = scal[1], lam = scal[3];
    int tx = threadIdx.x & 31, ty = threadIdx.x >> 5;
    #pragma unroll
    for (int s = 0; s < 32; s += 8) {
        int r = rb + ty + s, c = cb + tx;
        float g = softt(eta * Bm[(size_t)r * NF_ + c], lam);
        Gamma[(size_t)r * NF_ + c] = g;
        t[ty + s][tx] = g;
    }
    __syncthreads();
    #pragma unroll
    for (int s = 0; s < 32; s += 8) {
        int c = cb + ty + s, r = rb + tx;
        float v = t[tx][ty + s];
        _Float16 h = (_Float16)v;
        size_t o = (size_t)c * MD_ + r;
        Zh[o] = h;
        Zl[o] = (_Float16)(v - (float)h);
    }
}

// ---------- cooperative power method: 6x H4 (=G^16 each) + 4x G = 100 applies ----------
#define P2ITER 10
__global__ __launch_bounds__(256)
void power2_kernel(const _Float16* __restrict__ Hh, const _Float16* __restrict__ Hl,
                   const _Float16* __restrict__ Eh, const _Float16* __restrict__ El,
                   const int* __restrict__ Kp,
                   float* __restrict__ scal, float* __restrict__ Xa, float* __restrict__ Xb) {
    cg::grid_group grid = cg::this_grid();
    __shared__ float xs[MD_];
    __shared__ float red[8];
    const int tid = threadIdx.x, bid = blockIdx.x;
    const int w = tid >> 6, l = tid & 63;
    const int r0 = bid * 8;    // 256 blocks x 8 rows = 2048

    for (int it = 0; it < P2ITER; ++it) {
        const float* Xc = (it & 1) ? Xb : Xa;
        float* Xn = (it & 1) ? Xa : Xb;
        float ss = 0.f;
        for (int k = tid; k < MD_; k += 256) { float v = Xc[k]; xs[k] = v; ss += v * v; }
        __syncthreads();
        ss = blockReduceSum(ss, red);
        float inv = 1.0f / sqrtf(ss);
        const bool gphase = (it >= P2ITER - 4);           // last 4: apply G = E + I
        const _Float16* mh = gphase ? Eh : Hh;
        const _Float16* ml = gphase ? El : Hl;
        #pragma unroll
        for (int rr = 0; rr < 2; ++rr) {
            int r = r0 + w * 2 + rr;
            const _Float16* mhr = mh + (size_t)r * MD_;
            const _Float16* mlr = ml + (size_t)r * MD_;
            float s = 0.f;
            #pragma unroll
            for (int q = 0; q < 8; ++q) {
                int o = (q * 64 + l) * 4;
                half4_t hv = *reinterpret_cast<const half4_t*>(mhr + o);
                half4_t lv = *reinterpret_cast<const half4_t*>(mlr + o);
                float4 xv = *reinterpret_cast<const float4*>(&xs[o]);
                s = fmaf((float)hv[0] + (float)lv[0], xv.x, s);
                s = fmaf((float)hv[1] + (float)lv[1], xv.y, s);
                s = fmaf((float)hv[2] + (float)lv[2], xv.z, s);
                s = fmaf((float)hv[3] + (float)lv[3], xv.w, s);
            }
            #pragma unroll
            for (int off = 32; off; off >>= 1) s += __shfl_down(s, off);
            if (l == 0) Xn[r] = (s + (gphase ? xs[r] : 0.f)) * inv;
        }
        grid.sync();
    }
    if (bid == 0) {
        const float* Xf = ((P2ITER - 1) & 1) ? Xa : Xb;
        float ss = 0.f;
        for (int k = tid; k < MD_; k += 256) { float v = Xf[k]; ss += v * v; }
        ss = blockReduceSum(ss, red);
        if (tid == 0) {
            float c = sqrtf(ss);
            float lam = (float)Kp[0];
            scal[0] = c;
            scal[1] = 1.0f / c;
            scal[2] = lam / c;
            scal[3] = lam;
        }
    }
}

// ---------- split-f16 MFMA GEMM, 128x128 tile, BK=32 ----------
// THREE=true: 3-product (AhBh + AhBl + AlBh). THREE=false: 2-product (AhBh + AhBl),
// used for FISTA where A = E (|E|<~0.1, dropped AlBh term ~2e-4 relative).
enum { ME_STORE = 0, ME_SYMSPLIT = 1, ME_SYMSPLIT_MI = 2, ME_H1 = 3, ME_SPLIT_T = 4,
       ME_FISTAG = 5, ME_FISTAG_LAST = 6, ME_BIAS = 7, ME_BIASRELU = 8 };

__device__ __forceinline__ void stage_h(const _Float16* __restrict__ g, int row0, int K, int kk,
                                        _Float16* s, int w, int l) {
    #pragma unroll
    for (int p = 0; p < 2; ++p) {
        int c = p * 256 + w * 64 + l;                       // chunk id, lanes contiguous
        const _Float16* gp = g + (size_t)(row0 + (c >> 2)) * K + kk + ((c & 3) << 3);
        _Float16* lp = s + ((size_t)(p * 256 + w * 64) << 3);   // wave-uniform base
        __builtin_amdgcn_global_load_lds(
            (const __attribute__((address_space(1))) void*)gp,
            (__attribute__((address_space(3))) void*)lp, 16, 0, 0);
    }
}

template <bool AFP32, bool THREE>
__global__ __launch_bounds__(256)
void mgemm_kernel(const _Float16* __restrict__ Ah, const _Float16* __restrict__ Al,
                  const float* __restrict__ Afp, int Marr,
                  const _Float16* __restrict__ Bh, const _Float16* __restrict__ Bl,
                  int K, int Mvalid, int Nvalid, int ldc,
                  float* __restrict__ C, const float* __restrict__ BmP,
                  const float* __restrict__ bias,
                  _Float16* __restrict__ Th, _Float16* __restrict__ Tl, int Tstride,
                  const float* __restrict__ scal, float betak,
                  float* __restrict__ nrm_acc, int epi) {
    __shared__ __align__(16) _Float16 sAh[128 * 32], sAl[128 * 32];
    __shared__ __align__(16) _Float16 sBh[128 * 32], sBl[128 * 32];
    __shared__ float red[8];
    const int tid = threadIdx.x;
    const int w = tid >> 6, l = tid & 63;
    const int wr = w >> 1, wc = w & 1;
    const int quad = l >> 4, lc = l & 15;
    const int row0 = blockIdx.y * 128, col0 = blockIdx.x * 128;

    floatx4_t acc[4][4];
    #pragma unroll
    for (int i = 0; i < 4; ++i)
        #pragma unroll
        for (int j = 0; j < 4; ++j) {
            floatx4_t z = {0.f, 0.f, 0.f, 0.f};
            acc[i][j] = z;
        }

    for (int kk = 0; kk < K; kk += 32) {
        if constexpr (AFP32) {
            #pragma unroll
            for (int p = 0; p < 4; ++p) {
                int c2 = p * 256 + tid;                 // 0..1023
                int r = c2 >> 3, k4 = (c2 & 7) << 2;
                int gr = row0 + r;
                gr = gr < Marr ? gr : Marr - 1;         // clamp; masked at store
                float4 v = *reinterpret_cast<const float4*>(Afp + (size_t)gr * K + kk + k4);
                half4_t hh, ll;
                hh[0] = (_Float16)v.x; ll[0] = (_Float16)(v.x - (float)hh[0]);
                hh[1] = (_Float16)v.y; ll[1] = (_Float16)(v.y - (float)hh[1]);
                hh[2] = (_Float16)v.z; ll[2] = (_Float16)(v.z - (float)hh[2]);
                hh[3] = (_Float16)v.w; ll[3] = (_Float16)(v.w - (float)hh[3]);
                *reinterpret_cast<half4_t*>(&sAh[r * 32 + k4]) = hh;
                *reinterpret_cast<half4_t*>(&sAl[r * 32 + k4]) = ll;
            }
        } else {
            stage_h(Ah, row0, K, kk, sAh, w, l);
            if constexpr (THREE) stage_h(Al, row0, K, kk, sAl, w, l);
        }
        stage_h(Bh, col0, K, kk, sBh, w, l);
        stage_h(Bl, col0, K, kk, sBl, w, l);
        asm volatile("s_waitcnt vmcnt(0)" ::: "memory");
        __syncthreads();

        half8_t fAh[4], fAl[4], fBh[4], fBl[4];
        #pragma unroll
        for (int i = 0; i < 4; ++i) {
            int oa = (wr * 64 + i * 16 + lc) * 32 + quad * 8;
            fAh[i] = *reinterpret_cast<const half8_t*>(&sAh[oa]);
            if constexpr (THREE) fAl[i] = *reinterpret_cast<const half8_t*>(&sAl[oa]);
            int ob = (wc * 64 + i * 16 + lc) * 32 + quad * 8;
            fBh[i] = *reinterpret_cast<const half8_t*>(&sBh[ob]);
            fBl[i] = *reinterpret_cast<const half8_t*>(&sBl[ob]);
        }
        #pragma unroll
        for (int i = 0; i < 4; ++i)
            #pragma unroll
            for (int j = 0; j < 4; ++j) {
                acc[i][j] = __builtin_amdgcn_mfma_f32_16x16x32_f16(fAh[i], fBh[j], acc[i][j], 0, 0, 0);
                acc[i][j] = __builtin_amdgcn_mfma_f32_16x16x32_f16(fAh[i], fBl[j], acc[i][j], 0, 0, 0);
                if constexpr (THREE)
                    acc[i][j] = __builtin_amdgcn_mfma_f32_16x16x32_f16(fAl[i], fBh[j], acc[i][j], 0, 0, 0);
            }
        __syncthreads();
    }

    float eta = 0.f, thr = 0.f;
    if (epi == ME_FISTAG || epi == ME_FISTAG_LAST) { eta = scal[1]; thr = scal[2]; }
    float rsq = 0.f;
    #pragma unroll
    for (int i = 0; i < 4; ++i) {
        int grow0 = row0 + wr * 64 + i * 16 + quad * 4;
        bool rowok = grow0 < Mvalid;
        #pragma unroll
        for (int j = 0; j < 4; ++j) {
            int gcol = col0 + wc * 64 + j * 16 + lc;
            bool colok = gcol < Nvalid;
            floatx4_t v = acc[i][j];
            if (epi == ME_STORE) {
                if (rowok && colok) {
                    #pragma unroll
                    for (int r = 0; r < 4; ++r) C[(size_t)(grow0 + r) * ldc + gcol] = v[r];
                }
            } else if (epi == ME_SYMSPLIT || epi == ME_SYMSPLIT_MI || epi == ME_H1) {
                #pragma unroll
                for (int r = 0; r < 4; ++r) {
                    float vv = v[r];
                    float dg = ((grow0 + r) == gcol) ? 1.f : 0.f;
                    size_t o = (size_t)(grow0 + r) * Tstride + gcol;
                    if (epi == ME_SYMSPLIT_MI) {
                        vv -= dg;                        // E = G - I
                    } else if (epi == ME_H1) {
                        // H1 = (E^2 + 2E + I)/16 = G^2/16 ; E re-read from A operand
                        float ev = (float)Ah[o] + (float)Al[o];
                        vv = (vv + 2.f * ev + dg) * 0.0625f;
                    }
                    _Float16 h = (_Float16)vv;
                    Th[o] = h;
                    Tl[o] = (_Float16)(vv - (float)h);
                }
            } else if (epi == ME_SPLIT_T) {
                if (rowok && colok) {
                    half4_t hh, ll;
                    #pragma unroll
                    for (int r = 0; r < 4; ++r) {
                        _Float16 h = (_Float16)v[r];
                        hh[r] = h; ll[r] = (_Float16)(v[r] - (float)h);
                    }
                    size_t to = (size_t)gcol * Tstride + grow0;
                    *reinterpret_cast<half4_t*>(&Th[to]) = hh;
                    *reinterpret_cast<half4_t*>(&Tl[to]) = ll;
                }
            } else if (epi == ME_FISTAG || epi == ME_FISTAG_LAST) {
                // A = E so acc = (EZ); GZ = acc + Z. Z_in read from B operand buffer,
                // Z_out -> Th/Tl (distinct ping-pong buffer, race-free)
                size_t to = (size_t)gcol * Tstride + grow0;
                half4_t zh = *reinterpret_cast<const half4_t*>(&Bh[to]);
                half4_t zl = *reinterpret_cast<const half4_t*>(&Bl[to]);
                half4_t oh, ol;
                #pragma unroll
                for (int r = 0; r < 4; ++r) {
                    float z = (float)zh[r] + (float)zl[r];
                    float p = v[r] + z;                          // GZ
                    float bi = BmP[(size_t)(grow0 + r) * NF_ + gcol];
                    rsq = fmaf(z, p - 2.0f * bi, rsq);           // <Z,GZ> - 2<Z,B>
                    float g = z - eta * (p - bi);
                    float gn = softt(g, thr);
                    size_t ci = (size_t)(grow0 + r) * NF_ + gcol;
                    float gold = C[ci];
                    C[ci] = gn;
                    float zo = (epi == ME_FISTAG) ? (gn + betak * (gn - gold)) : gn;
                    _Float16 h = (_Float16)zo;
                    oh[r] = h; ol[r] = (_Float16)(zo - (float)h);
                }
                *reinterpret_cast<half4_t*>(&Th[to]) = oh;
                *reinterpret_cast<half4_t*>(&Tl[to]) = ol;
            } else {   // ME_BIAS / ME_BIASRELU
                if (rowok && colok) {
                    #pragma unroll
                    for (int r = 0; r < 4; ++r) {
                        float s = v[r] + bias[gcol];
                        if (epi == ME_BIASRELU) s = s > 0.f ? s : 0.f;
                        C[(size_t)(grow0 + r) * ldc + gcol] = s;
                    }
                }
            }
        }
    }
    if (epi == ME_FISTAG || epi == ME_FISTAG_LAST) {
        float tot = blockReduceSum(rsq, red);
        if (tid == 0) atomicAdd(nrm_acc, tot);
    }
}

__global__ void logsoftmax_kernel(const float* __restrict__ O, float* __restrict__ out) {
    int row = blockIdx.x * 4 + (threadIdx.x >> 6);
    int lane = threadIdx.x & 63;
    if (row >= NN_) return;
    float v = O[row * NC_ + lane];
    float m = v;
    #pragma unroll
    for (int off = 32; off; off >>= 1) m = fmaxf(m, __shfl_xor(m, off));
    float e = expf(v - m);
    float s = e;
    #pragma unroll
    for (int off = 32; off; off >>= 1) s += __shfl_xor(s, off);
    out[row * NC_ + lane] = (v - m) - logf(s);
}

__global__ void norms_kernel(const float* __restrict__ scal, float* __restrict__ nout) {
    int k = threadIdx.x;
    if (k < FITER) {
        float ysq = scal[4];
        float v = scal[5 + k] + ysq;            // ||WZ-Y||^2 via Gram identity
        nout[k] = sqrtf(fmaxf(v, 0.f)) / sqrtf(ysq);
    }
}

static inline void launch_m(bool afp32, bool three, dim3 grid,
                            const _Float16* Ah, const _Float16* Al,
                            const float* Afp, int Marr,
                            const _Float16* Bh, const _Float16* Bl,
                            int K, int Mvalid, int Nvalid, int ldc,
                            float* C, const float* BmP, const float* bias,
                            _Float16* Th, _Float16* Tl, int Tstride,
                            const float* scal, float betak, float* nrm, int epi,
                            hipStream_t s) {
    if (afp32)
        mgemm_kernel<true, true><<<grid, dim3(256), 0, s>>>(
            Ah, Al, Afp, Marr, Bh, Bl, K, Mvalid, Nvalid, ldc, C, BmP, bias,
            Th, Tl, Tstride, scal, betak, nrm, epi);
    else if (three)
        mgemm_kernel<false, true><<<grid, dim3(256), 0, s>>>(
            Ah, Al, Afp, Marr, Bh, Bl, K, Mvalid, Nvalid, ldc, C, BmP, bias,
            Th, Tl, Tstride, scal, betak, nrm, epi);
    else
        mgemm_kernel<false, false><<<grid, dim3(256), 0, s>>>(
            Ah, Al, Afp, Marr, Bh, Bl, K, Mvalid, Nvalid, ldc, C, BmP, bias,
            Th, Tl, Tstride, scal, betak, nrm, epi);
}

extern "C" void kernel_launch(void* const* d_in, const int* in_sizes, int n_in,
                              void* d_out, int out_size, void* d_ws, size_t ws_size,
                              hipStream_t stream) {
    const float* x     = (const float*)d_in[0];   // (2708, 4096)
    const float* adj   = (const float*)d_in[1];   // (2708, 2708)
    const float* gc1_w = (const float*)d_in[2];   // (4096, 1024)
    const float* gc1_b = (const float*)d_in[3];   // (1024,)
    const float* gc2_w = (const float*)d_in[4];   // (1024, 64)
    const float* gc2_b = (const float*)d_in[5];   // (64,)
    const float* Wd    = (const float*)d_in[6];   // (2708, 2048)
    const int*   Kp    = (const int*)d_in[7];     // scalar K

    float* out = (float*)d_out;
    float* logp    = out;                                     // (2708, 64)
    float* x_dec   = logp + (size_t)NN_ * NC_;                // (2708, 4096)
    float* Gamma   = x_dec + (size_t)NN_ * NF_;               // (2048, 4096)
    float* norms_o = Gamma + (size_t)MD_ * NF_;               // (20,)

    // ---- ws layout: 100,679,808 B (same proven footprint) ----
    char* wsb = (char*)d_ws;
    const size_t OFF_R1 = 16512;                       // after scal/Xa/Xb
    const size_t OFF_R2 = OFF_R1 + 16777216;           // Eh/El (16.78 MB)
    const size_t OFF_R3 = OFF_R2 + 33554432;           // Bm (33.55 MB)
    const size_t OFF_R4 = OFF_R3 + 33554432;           // R3: Wt+xth -> H pong -> ZtA
    float* scal = (float*)wsb;
    float* Xa   = scal + 32;
    float* Xb   = Xa + MD_;
    _Float16* Eh = (_Float16*)(wsb + OFF_R1);          // E = G - I, split
    _Float16* El = Eh + (size_t)MD_ * MD_;
    float* Bm = (float*)(wsb + OFF_R2);
    // R3 phase 1: Wt + xth_hi
    _Float16* Wt_hi  = (_Float16*)(wsb + OFF_R3);
    _Float16* Wt_lo  = Wt_hi + (size_t)MD_ * KPAD;
    _Float16* xth_hi = Wt_lo + (size_t)MD_ * KPAD;     // 11.14 MB, fits slack
    _Float16* xth_lo = (_Float16*)(wsb + OFF_R4);      // R4 phase 1 (11.14 <= 16.78)
    // H squaring chain ping-pong: HA in R4 (16.78 MB), HB in first 16.78 MB of R3
    _Float16* HA_hi = (_Float16*)(wsb + OFF_R4);
    _Float16* HA_lo = HA_hi + (size_t)MD_ * MD_;
    _Float16* HB_hi = (_Float16*)(wsb + OFF_R3);
    _Float16* HB_lo = HB_hi + (size_t)MD_ * MD_;
    // R3 phase 2: ZtA (4096 x 2048 split, ping) — after power2 consumes HB
    _Float16* ZA_hi = (_Float16*)(wsb + OFF_R3);
    _Float16* ZA_lo = ZA_hi + (size_t)NF_ * MD_;
    // pong: the x_dec slab of d_out (44.4 MB >= 33.55 MB), scratch until phase 3
    _Float16* ZB_hi = (_Float16*)x_dec;
    _Float16* ZB_lo = ZB_hi + (size_t)NF_ * MD_;
    // R2 phase 3: adj split [2816][2720]
    _Float16* adjT_hi = (_Float16*)(wsb + OFF_R2);
    _Float16* adjT_lo = adjT_hi + (size_t)2816 * KPAD;
    // R1 phase 3: gc1^T split [1024][4096]
    _Float16* g1t_hi = (_Float16*)(wsb + OFF_R1);
    _Float16* g1t_lo = g1t_hi + (size_t)NH_ * NF_;
    // R3 phase 3
    _Float16* xwT_hi = (_Float16*)(wsb + OFF_R3);                  // [1024][2720]
    _Float16* xwT_lo = xwT_hi + (size_t)NH_ * KPAD;
    float*    hbuf   = (float*)(wsb + OFF_R3 + 11141120);          // [2708][1024]
    _Float16* hwT_hi = (_Float16*)(wsb + OFF_R3 + 22233088);       // [128][2720]
    _Float16* hwT_lo = hwT_hi + (size_t)128 * KPAD;
    _Float16* g2t_hi = (_Float16*)(wsb + OFF_R3 + 23625728);       // [128][1024]
    _Float16* g2t_lo = g2t_hi + (size_t)128 * NH_;
    float*    obuf   = (float*)(wsb + OFF_R3 + 24150016);          // [2708][64]

    const _Float16* nullh = nullptr;
    float* nullf = nullptr;

    // ---- phase 1: init, E = W^T W - I, B = W^T Y, squaring chain, power, Gamma0 ----
    zero_scal_kernel<<<1, 64, 0, stream>>>(scal);
    init_x0_kernel<<<4, 256, 0, stream>>>(Xa);
    sumsq_kernel<<<1024, 256, 0, stream>>>(x, NN_ * NF_, scal + 4);

    tsplit_kernel<<<dim3(MD_ / 32, KPAD / 32), 256, 0, stream>>>(Wd, NN_, MD_, KPAD, Wt_hi, Wt_lo);
    // E = W^T W - I (split output)
    launch_m(false, true, dim3(16, 16), Wt_hi, Wt_lo, nullptr, 0, Wt_hi, Wt_lo,
             KPAD, MD_, MD_, 0, nullf, nullptr, nullptr, Eh, El, MD_,
             scal, 0.f, nullptr, ME_SYMSPLIT_MI, stream);
    // B = W^T Y in two N-halves (xth buffer reused)
    for (int half = 0; half < 2; ++half) {
        tsplit_kernel<<<dim3(MD_ / 32, KPAD / 32), 256, 0, stream>>>(
            x + half * 2048, NN_, NF_, KPAD, xth_hi, xth_lo);
        launch_m(false, true, dim3(16, 16), Wt_hi, Wt_lo, nullptr, 0, xth_hi, xth_lo,
                 KPAD, MD_, MD_, NF_, Bm + half * 2048, nullptr, nullptr,
                 nullptr, nullptr, 0, scal, 0.f, nullptr, ME_STORE, stream);
    }
    // squaring chain: H1 = G^2/16 (from E), H2 = H1^2, H3 = H2^2, H4 = H3^2 (= G^16/2^32)
    launch_m(false, true, dim3(16, 16), Eh, El, nullptr, 0, Eh, El,
             MD_, MD_, MD_, 0, nullf, nullptr, nullptr, HA_hi, HA_lo, MD_,
             scal, 0.f, nullptr, ME_H1, stream);
    launch_m(false, true, dim3(16, 16), HA_hi, HA_lo, nullptr, 0, HA_hi, HA_lo,
             MD_, MD_, MD_, 0, nullf, nullptr, nullptr, HB_hi, HB_lo, MD_,
             scal, 0.f, nullptr, ME_SYMSPLIT, stream);
    launch_m(false, true, dim3(16, 16), HB_hi, HB_lo, nullptr, 0, HB_hi, HB_lo,
             MD_, MD_, MD_, 0, nullf, nullptr, nullptr, HA_hi, HA_lo, MD_,
             scal, 0.f, nullptr, ME_SYMSPLIT, stream);
    launch_m(false, true, dim3(16, 16), HA_hi, HA_lo, nullptr, 0, HA_hi, HA_lo,
             MD_, MD_, MD_, 0, nullf, nullptr, nullptr, HB_hi, HB_lo, MD_,
             scal, 0.f, nullptr, ME_SYMSPLIT, stream);
    // cooperative power: 6x H4 + 4x G (= exactly 100 G-applies)
    {
        void* args[] = {(void*)&HB_hi, (void*)&HB_lo, (void*)&Eh, (void*)&El,
                        (void*)&Kp, (void*)&scal, (void*)&Xa, (void*)&Xb};
        hipLaunchCooperativeKernel((void*)power2_kernel, dim3(256), dim3(256), args, 0, stream);
    }
    // Gamma0 = soft(eta*B, lam); ZtA = split(Gamma0^T)  (overwrites HB — dead now)
    g0_kernel<<<dim3(NF_ / 32, MD_ / 32), 256, 0, stream>>>(Bm, scal, Gamma, ZA_hi, ZA_lo);

    // ---- phase 2: FISTA in Gram domain, A = E (2-product), Z ping-pong ----
    {
        float t = 1.f;
        for (int k = 0; k < FITER; ++k) {
            float tn = (1.0f + sqrtf(1.0f + (4.0f * t) * t)) / 2.0f;
            float beta = (t - 1.0f) / tn;
            t = tn;
            _Float16* in_hi  = (k & 1) ? ZB_hi : ZA_hi;
            _Float16* in_lo  = (k & 1) ? ZB_lo : ZA_lo;
            _Float16* out_hi = (k & 1) ? ZA_hi : ZB_hi;
            _Float16* out_lo = (k & 1) ? ZA_lo : ZB_lo;
            launch_m(false, false, dim3(32, 16), Eh, El, nullptr, 0, in_hi, in_lo,
                     MD_, MD_, NF_, NF_, Gamma, Bm, nullptr,
                     out_hi, out_lo, MD_, scal, beta, scal + 5 + k,
                     (k == FITER - 1) ? ME_FISTAG_LAST : ME_FISTAG, stream);
        }
        // FITER=20 even: final Gamma-split lands in ZA (ws); ZB (x_dec slab) is dead
    }

    // ---- phase 3: decode + GCN tail (all MFMA) ----
    splitadj_kernel<<<2816, 256, 0, stream>>>(adj, adjT_hi, adjT_lo);
    // x_dec = W @ Gamma  (ZA holds split Gamma^T; output overwrites the dead ZB slab)
    launch_m(true, true, dim3(32, 22), nullh, nullh, Wd, NN_, ZA_hi, ZA_lo,
             MD_, NN_, NF_, NF_, x_dec, nullptr, nullptr,
             nullptr, nullptr, 0, scal, 0.f, nullptr, ME_STORE, stream);
    tsplit_kernel<<<dim3(NH_ / 32, NF_ / 32), 256, 0, stream>>>(gc1_w, NF_, NH_, NF_, g1t_hi, g1t_lo);
    fill0_kernel<<<(2785280 + 255) / 256, 256, 0, stream>>>((uint32_t*)xwT_hi, 2785280);
    // xw^T = split((x_dec @ gc1_w)^T)
    launch_m(true, true, dim3(8, 22), nullh, nullh, x_dec, NN_, g1t_hi, g1t_lo,
             NF_, NN_, NH_, 0, nullf, nullptr, nullptr,
             xwT_hi, xwT_lo, KPAD, scal, 0.f, nullptr, ME_SPLIT_T, stream);
    // h = relu(adj @ xw + b1)
    launch_m(false, true, dim3(8, 22), adjT_hi, adjT_lo, nullptr, 0, xwT_hi, xwT_lo,
             KPAD, NN_, NH_, NH_, hbuf, nullptr, gc1_b,
             nullptr, nullptr, 0, scal, 0.f, nullptr, ME_BIASRELU, stream);
    fill0_kernel<<<(131072 + 255) / 256, 256, 0, stream>>>((uint32_t*)g2t_hi, 131072);
    tsplit_kernel<<<dim3(NC_ / 32, NH_ / 32), 256, 0, stream>>>(gc2_w, NH_, NC_, NH_, g2t_hi, g2t_lo);
    fill0_kernel<<<(348160 + 255) / 256, 256, 0, stream>>>((uint32_t*)hwT_hi, 348160);
    // hw^T = split((h @ gc2_w)^T)
    launch_m(true, true, dim3(1, 22), nullh, nullh, hbuf, NN_, g2t_hi, g2t_lo,
             NH_, NN_, NC_, 0, nullf, nullptr, nullptr,
             hwT_hi, hwT_lo, KPAD, scal, 0.f, nullptr, ME_SPLIT_T, stream);
    // o = adj @ hw + b2
    launch_m(false, true, dim3(1, 22), adjT_hi, adjT_lo, nullptr, 0, hwT_hi, hwT_lo,
             KPAD, NN_, NC_, NC_, obuf, nullptr, gc2_b,
             nullptr, nullptr, 0, scal, 0.f, nullptr, ME_BIAS, stream);
    logsoftmax_kernel<<<(NN_ + 3) / 4, 256, 0, stream>>>(obuf, logp);
    norms_kernel<<<1, 32, 0, stream>>>(scal, norms_o);
}

// Round 6
// 4216.388 us; speedup vs baseline: 8.8757x; 1.0659x over previous
//
#include <hip/hip_runtime.h>
#include <hip/hip_cooperative_groups.h>
#include <cstdint>
#include <cmath>

namespace cg = cooperative_groups;

#define NN_ 2708
#define NF_ 4096
#define MD_ 2048
#define NH_ 1024
#define NC_ 64
#define FITER 20
#define KPAD 2720   // 2708 padded to multiple of 32

// scal layout (floats in ws): [0]=c [1]=eta [2]=thr(lam/c) [3]=lam [4]=ynormsq [5..24]=rsq[k]

typedef _Float16 half8_t __attribute__((ext_vector_type(8)));
typedef _Float16 half4_t __attribute__((ext_vector_type(4)));
typedef float floatx4_t __attribute__((ext_vector_type(4)));

__device__ __forceinline__ float softt(float v, float t) {
    float a = fabsf(v) - t;
    a = a > 0.f ? a : 0.f;
    return copysignf(a, v);
}

__device__ __forceinline__ float blockReduceSum(float v, float* red) {
    int lane = threadIdx.x & 63, wid = threadIdx.x >> 6;
    #pragma unroll
    for (int off = 32; off; off >>= 1) v += __shfl_down(v, off);
    if (lane == 0) red[wid] = v;
    __syncthreads();
    if (wid == 0) {
        int nw = (blockDim.x + 63) >> 6;
        float r = (lane < nw) ? red[lane] : 0.f;
        #pragma unroll
        for (int off = 2; off; off >>= 1) r += __shfl_down(r, off);
        if (lane == 0) red[0] = r;
    }
    __syncthreads();
    float out = red[0];
    __syncthreads();
    return out;
}

// ---------- threefry2x32 + JAX normal init ----------
__device__ __forceinline__ float erfinv_f(float x) {
    float w = -log1pf(-x * x);
    float p;
    if (w < 5.0f) {
        w -= 2.5f;
        p = 2.81022636e-08f;
        p = fmaf(p, w, 3.43273939e-07f);
        p = fmaf(p, w, -3.5233877e-06f);
        p = fmaf(p, w, -4.39150654e-06f);
        p = fmaf(p, w, 0.00021858087f);
        p = fmaf(p, w, -0.00125372503f);
        p = fmaf(p, w, -0.00417768164f);
        p = fmaf(p, w, 0.246640727f);
        p = fmaf(p, w, 1.50140941f);
    } else {
        w = sqrtf(w) - 3.0f;
        p = -0.000200214257f;
        p = fmaf(p, w, 0.000100950558f);
        p = fmaf(p, w, 0.00134934322f);
        p = fmaf(p, w, -0.00367342844f);
        p = fmaf(p, w, 0.00573950773f);
        p = fmaf(p, w, -0.0076224613f);
        p = fmaf(p, w, 0.00943887047f);
        p = fmaf(p, w, 1.00167406f);
        p = fmaf(p, w, 2.83297682f);
    }
    return p * x;
}

__device__ __forceinline__ float u32_to_normal(uint32_t bits) {
    uint32_t fb = (bits >> 9) | 0x3F800000u;
    float f = __uint_as_float(fb) - 1.0f;        // [0,1)
    const float lo = -0.99999994f;               // nextafter(-1,0) in f32
    float u = fmaf(f, 2.0f, lo);
    u = fmaxf(lo, u);
    return 1.41421356f * erfinv_f(u);
}

__global__ void init_x0_kernel(float* __restrict__ X0) {
    int i = blockIdx.x * blockDim.x + threadIdx.x;   // 0..1023 pairs
    if (i >= MD_ / 2) return;
    uint32_t x0 = (uint32_t)i, x1 = (uint32_t)(i + MD_ / 2);
    const uint32_t k0 = 0u, k1 = 1u, k2 = 0x1BD11BDBu;
    const uint32_t ks[3] = {k0, k1, k2};
    x0 += k0; x1 += k1;
    const int rot[8] = {13, 15, 26, 6, 17, 29, 16, 24};
    #pragma unroll
    for (int g = 0; g < 5; ++g) {
        const int base = (g & 1) ? 4 : 0;
        #pragma unroll
        for (int rr = 0; rr < 4; ++rr) {
            x0 += x1;
            int r = rot[base + rr];
            x1 = (x1 << r) | (x1 >> (32 - r));
            x1 ^= x0;
        }
        x0 += ks[(g + 1) % 3];
        x1 += ks[(g + 2) % 3] + (uint32_t)(g + 1);
    }
    X0[i] = u32_to_normal(x0);
    X0[i + MD_ / 2] = u32_to_normal(x1);
}

__global__ void zero_scal_kernel(float* __restrict__ scal) {
    int t = threadIdx.x;
    if (t < 32) scal[t] = 0.f;
}

__global__ void fill0_kernel(uint32_t* __restrict__ p, int n32) {
    int i = blockIdx.x * blockDim.x + threadIdx.x;
    if (i < n32) p[i] = 0u;
}

__global__ void sumsq_kernel(const float* __restrict__ X, int n, float* __restrict__ acc) {
    __shared__ float red[8];
    float s = 0.f;
    for (size_t i = (size_t)blockIdx.x * blockDim.x + threadIdx.x; i < (size_t)n;
         i += (size_t)gridDim.x * blockDim.x) {
        float v = X[i];
        s += v * v;
    }
    s = blockReduceSum(s, red);
    if (threadIdx.x == 0) atomicAdd(acc, s);
}

// ---------- transpose + split fp32 -> f16 hi/lo, out[c][r] padded to Rpad ----------
__global__ void tsplit_kernel(const float* __restrict__ src, int R, int ld, int Rpad,
                              _Float16* __restrict__ hi, _Float16* __restrict__ lo) {
    __shared__ float t[32][33];
    int rb = blockIdx.y * 32, cb = blockIdx.x * 32;
    int tx = threadIdx.x & 31, ty = threadIdx.x >> 5;   // ty 0..7
    #pragma unroll
    for (int s = 0; s < 32; s += 8) {
        int r = rb + ty + s, c = cb + tx;
        t[ty + s][tx] = (r < R) ? src[(size_t)r * ld + c] : 0.f;
    }
    __syncthreads();
    #pragma unroll
    for (int s = 0; s < 32; s += 8) {
        int c = cb + ty + s, r = rb + tx;
        float v = t[tx][ty + s];
        _Float16 h = (_Float16)v;
        size_t o = (size_t)c * Rpad + r;
        hi[o] = h;
        lo[o] = (_Float16)(v - (float)h);
    }
}

// ---------- fp32 -> f16 hi-only, non-transposed, zero row-padding ----------
// grid.x = Rpad, rows >= R write zeros; C multiple of 4
__global__ void splitrows_hi_kernel(const float* __restrict__ src, int R, int C,
                                    _Float16* __restrict__ hi) {
    int r = blockIdx.x;
    _Float16* d = hi + (size_t)r * C;
    if (r < R) {
        const float* s = src + (size_t)r * C;
        for (int c = threadIdx.x * 4; c < C; c += 1024) {
            float4 v = *reinterpret_cast<const float4*>(s + c);
            half4_t h;
            h[0] = (_Float16)v.x; h[1] = (_Float16)v.y;
            h[2] = (_Float16)v.z; h[3] = (_Float16)v.w;
            *reinterpret_cast<half4_t*>(d + c) = h;
        }
    } else {
        for (int c = threadIdx.x * 4; c < C; c += 1024) {
            half4_t h = {(_Float16)0.f, (_Float16)0.f, (_Float16)0.f, (_Float16)0.f};
            *reinterpret_cast<half4_t*>(d + c) = h;
        }
    }
}

// ---------- adj -> f16 hi-only, [2816][2720] zero-padded (2708 % 4 == 0) ----------
__global__ void splitadj_hi_kernel(const float* __restrict__ adj, _Float16* __restrict__ hi) {
    int r = blockIdx.x;   // 0..2815
    bool rok = r < NN_;
    _Float16* d = hi + (size_t)r * KPAD;
    const float* s = adj + (size_t)r * NN_;
    for (int c = threadIdx.x * 4; c < KPAD; c += 1024) {
        half4_t h = {(_Float16)0.f, (_Float16)0.f, (_Float16)0.f, (_Float16)0.f};
        if (rok && c + 3 < NN_) {
            float4 v = *reinterpret_cast<const float4*>(s + c);
            h[0] = (_Float16)v.x; h[1] = (_Float16)v.y;
            h[2] = (_Float16)v.z; h[3] = (_Float16)v.w;
        }
        *reinterpret_cast<half4_t*>(d + c) = h;
    }
}

// ---------- Gamma0 = soft(eta*B, lam); Zt = split(Gamma0^T) ----------
__global__ void g0_kernel(const float* __restrict__ Bm, const float* __restrict__ scal,
                          float* __restrict__ Gamma,
                          _Float16* __restrict__ Zh, _Float16* __restrict__ Zl) {
    __shared__ float t[32][33];
    int rb = blockIdx.y * 32;   // m-dim (2048)
    int cb = blockIdx.x * 32;   // nfeat (4096)
    float eta = scal[1], lam = scal[3];
    int tx = threadIdx.x & 31, ty = threadIdx.x >> 5;
    #pragma unroll
    for (int s = 0; s < 32; s += 8) {
        int r = rb + ty + s, c = cb + tx;
        float g = softt(eta * Bm[(size_t)r * NF_ + c], lam);
        Gamma[(size_t)r * NF_ + c] = g;
        t[ty + s][tx] = g;
    }
    __syncthreads();
    #pragma unroll
    for (int s = 0; s < 32; s += 8) {
        int c = cb + ty + s, r = rb + tx;
        float v = t[tx][ty + s];
        _Float16 h = (_Float16)v;
        size_t o = (size_t)c * MD_ + r;
        Zh[o] = h;
        Zl[o] = (_Float16)(v - (float)h);
    }
}

// ---------- cooperative power: 3x H5 (=G^32 each) + 4x G = exactly 100 applies ----------
#define P2ITER 7
__global__ __launch_bounds__(256)
void power2_kernel(const _Float16* __restrict__ Hh, const _Float16* __restrict__ Hl,
                   const _Float16* __restrict__ Eh, const _Float16* __restrict__ El,
                   const int* __restrict__ Kp,
                   float* __restrict__ scal, float* __restrict__ Xa, float* __restrict__ Xb) {
    cg::grid_group grid = cg::this_grid();
    __shared__ float xs[MD_];
    __shared__ float red[8];
    const int tid = threadIdx.x, bid = blockIdx.x;
    const int w = tid >> 6, l = tid & 63;
    const int r0 = bid * 8;    // 256 blocks x 8 rows = 2048

    for (int it = 0; it < P2ITER; ++it) {
        const float* Xc = (it & 1) ? Xb : Xa;
        float* Xn = (it & 1) ? Xa : Xb;
        float ss = 0.f;
        for (int k = tid; k < MD_; k += 256) { float v = Xc[k]; xs[k] = v; ss += v * v; }
        __syncthreads();
        ss = blockReduceSum(ss, red);
        float inv = 1.0f / sqrtf(ss);
        const bool gphase = (it >= P2ITER - 4);           // last 4: apply G = E + I
        const _Float16* mh = gphase ? Eh : Hh;
        const _Float16* ml = gphase ? El : Hl;
        #pragma unroll
        for (int rr = 0; rr < 2; ++rr) {
            int r = r0 + w * 2 + rr;
            const _Float16* mhr = mh + (size_t)r * MD_;
            const _Float16* mlr = ml + (size_t)r * MD_;
            float s = 0.f;
            #pragma unroll
            for (int q = 0; q < 8; ++q) {
                int o = (q * 64 + l) * 4;
                half4_t hv = *reinterpret_cast<const half4_t*>(mhr + o);
                half4_t lv = *reinterpret_cast<const half4_t*>(mlr + o);
                float4 xv = *reinterpret_cast<const float4*>(&xs[o]);
                s = fmaf((float)hv[0] + (float)lv[0], xv.x, s);
                s = fmaf((float)hv[1] + (float)lv[1], xv.y, s);
                s = fmaf((float)hv[2] + (float)lv[2], xv.z, s);
                s = fmaf((float)hv[3] + (float)lv[3], xv.w, s);
            }
            #pragma unroll
            for (int off = 32; off; off >>= 1) s += __shfl_down(s, off);
            if (l == 0) Xn[r] = (s + (gphase ? xs[r] : 0.f)) * inv;
        }
        grid.sync();
    }
    if (bid == 0) {
        const float* Xf = ((P2ITER - 1) & 1) ? Xa : Xb;
        float ss = 0.f;
        for (int k = tid; k < MD_; k += 256) { float v = Xf[k]; ss += v * v; }
        ss = blockReduceSum(ss, red);
        if (tid == 0) {
            float c = sqrtf(ss);
            float lam = (float)Kp[0];
            scal[0] = c;
            scal[1] = 1.0f / c;
            scal[2] = lam / c;
            scal[3] = lam;
        }
    }
}

// ---------- split-f16 MFMA GEMM, 128x128 tile, BK=32 ----------
// THREE=true: 3-product (AhBh + AhBl + AlBh). THREE=false: 2-product (AhBh + AhBl),
// dropped AlBh term ~2^-11 relative on A.
enum { ME_STORE = 0, ME_SYMSPLIT = 1, ME_SYMSPLIT_MI = 2, ME_H1 = 3, ME_SYMSPLIT16 = 4,
       ME_SPLIT_T = 5, ME_FISTAG = 6, ME_FISTAG_LAST = 7, ME_BIAS = 8, ME_BIASRELU = 9 };

__device__ __forceinline__ void stage_h(const _Float16* __restrict__ g, int row0, int K, int kk,
                                        _Float16* s, int w, int l) {
    #pragma unroll
    for (int p = 0; p < 2; ++p) {
        int c = p * 256 + w * 64 + l;                       // chunk id, lanes contiguous
        const _Float16* gp = g + (size_t)(row0 + (c >> 2)) * K + kk + ((c & 3) << 3);
        _Float16* lp = s + ((size_t)(p * 256 + w * 64) << 3);   // wave-uniform base
        __builtin_amdgcn_global_load_lds(
            (const __attribute__((address_space(1))) void*)gp,
            (__attribute__((address_space(3))) void*)lp, 16, 0, 0);
    }
}

template <bool AFP32, bool THREE>
__global__ __launch_bounds__(256)
void mgemm_kernel(const _Float16* __restrict__ Ah, const _Float16* __restrict__ Al,
                  const float* __restrict__ Afp, int Marr,
                  const _Float16* __restrict__ Bh, const _Float16* __restrict__ Bl,
                  int K, int Mvalid, int Nvalid, int ldc,
                  float* __restrict__ C, const float* __restrict__ BmP,
                  const float* __restrict__ bias,
                  _Float16* __restrict__ Th, _Float16* __restrict__ Tl, int Tstride,
                  const float* __restrict__ scal, float betak,
                  float* __restrict__ nrm_acc, int epi) {
    __shared__ __align__(16) _Float16 sAh[128 * 32], sAl[128 * 32];
    __shared__ __align__(16) _Float16 sBh[128 * 32], sBl[128 * 32];
    __shared__ float red[8];
    const int tid = threadIdx.x;
    const int w = tid >> 6, l = tid & 63;
    const int wr = w >> 1, wc = w & 1;
    const int quad = l >> 4, lc = l & 15;
    const int row0 = blockIdx.y * 128, col0 = blockIdx.x * 128;

    floatx4_t acc[4][4];
    #pragma unroll
    for (int i = 0; i < 4; ++i)
        #pragma unroll
        for (int j = 0; j < 4; ++j) {
            floatx4_t z = {0.f, 0.f, 0.f, 0.f};
            acc[i][j] = z;
        }

    for (int kk = 0; kk < K; kk += 32) {
        if constexpr (AFP32) {
            #pragma unroll
            for (int p = 0; p < 4; ++p) {
                int c2 = p * 256 + tid;                 // 0..1023
                int r = c2 >> 3, k4 = (c2 & 7) << 2;
                int gr = row0 + r;
                gr = gr < Marr ? gr : Marr - 1;         // clamp; masked at store
                float4 v = *reinterpret_cast<const float4*>(Afp + (size_t)gr * K + kk + k4);
                half4_t hh, ll;
                hh[0] = (_Float16)v.x; ll[0] = (_Float16)(v.x - (float)hh[0]);
                hh[1] = (_Float16)v.y; ll[1] = (_Float16)(v.y - (float)hh[1]);
                hh[2] = (_Float16)v.z; ll[2] = (_Float16)(v.z - (float)hh[2]);
                hh[3] = (_Float16)v.w; ll[3] = (_Float16)(v.w - (float)hh[3]);
                *reinterpret_cast<half4_t*>(&sAh[r * 32 + k4]) = hh;
                *reinterpret_cast<half4_t*>(&sAl[r * 32 + k4]) = ll;
            }
        } else {
            stage_h(Ah, row0, K, kk, sAh, w, l);
            if constexpr (THREE) stage_h(Al, row0, K, kk, sAl, w, l);
        }
        stage_h(Bh, col0, K, kk, sBh, w, l);
        stage_h(Bl, col0, K, kk, sBl, w, l);
        asm volatile("s_waitcnt vmcnt(0)" ::: "memory");
        __syncthreads();

        half8_t fAh[4], fAl[4], fBh[4], fBl[4];
        #pragma unroll
        for (int i = 0; i < 4; ++i) {
            int oa = (wr * 64 + i * 16 + lc) * 32 + quad * 8;
            fAh[i] = *reinterpret_cast<const half8_t*>(&sAh[oa]);
            if constexpr (THREE) fAl[i] = *reinterpret_cast<const half8_t*>(&sAl[oa]);
            int ob = (wc * 64 + i * 16 + lc) * 32 + quad * 8;
            fBh[i] = *reinterpret_cast<const half8_t*>(&sBh[ob]);
            fBl[i] = *reinterpret_cast<const half8_t*>(&sBl[ob]);
        }
        #pragma unroll
        for (int i = 0; i < 4; ++i)
            #pragma unroll
            for (int j = 0; j < 4; ++j) {
                acc[i][j] = __builtin_amdgcn_mfma_f32_16x16x32_f16(fAh[i], fBh[j], acc[i][j], 0, 0, 0);
                acc[i][j] = __builtin_amdgcn_mfma_f32_16x16x32_f16(fAh[i], fBl[j], acc[i][j], 0, 0, 0);
                if constexpr (THREE)
                    acc[i][j] = __builtin_amdgcn_mfma_f32_16x16x32_f16(fAl[i], fBh[j], acc[i][j], 0, 0, 0);
            }
        __syncthreads();
    }

    float eta = 0.f, thr = 0.f;
    if (epi == ME_FISTAG || epi == ME_FISTAG_LAST) { eta = scal[1]; thr = scal[2]; }
    float rsq = 0.f;
    #pragma unroll
    for (int i = 0; i < 4; ++i) {
        int grow0 = row0 + wr * 64 + i * 16 + quad * 4;
        bool rowok = grow0 < Mvalid;
        #pragma unroll
        for (int j = 0; j < 4; ++j) {
            int gcol = col0 + wc * 64 + j * 16 + lc;
            bool colok = gcol < Nvalid;
            floatx4_t v = acc[i][j];
            if (epi == ME_STORE) {
                if (rowok && colok) {
                    #pragma unroll
                    for (int r = 0; r < 4; ++r) C[(size_t)(grow0 + r) * ldc + gcol] = v[r];
                }
            } else if (epi == ME_SYMSPLIT || epi == ME_SYMSPLIT_MI || epi == ME_H1 ||
                       epi == ME_SYMSPLIT16) {
                #pragma unroll
                for (int r = 0; r < 4; ++r) {
                    float vv = v[r];
                    float dg = ((grow0 + r) == gcol) ? 1.f : 0.f;
                    size_t o = (size_t)(grow0 + r) * Tstride + gcol;
                    if (epi == ME_SYMSPLIT_MI) {
                        vv -= dg;                        // E = G - I
                    } else if (epi == ME_H1) {
                        // H1 = (Eh·E + 2E + I)/16 ≈ G^2/16 ; E re-read from A operand
                        float ev = (float)Ah[o] + (float)Al[o];
                        vv = (vv + 2.f * ev + dg) * 0.0625f;
                    } else if (epi == ME_SYMSPLIT16) {
                        vv *= 16.f;                      // H5 = 16·H4^2, keeps f16-normal range
                    }
                    _Float16 h = (_Float16)vv;
                    Th[o] = h;
                    Tl[o] = (_Float16)(vv - (float)h);
                }
            } else if (epi == ME_SPLIT_T) {
                if (rowok && colok) {
                    half4_t hh, ll;
                    #pragma unroll
                    for (int r = 0; r < 4; ++r) {
                        _Float16 h = (_Float16)v[r];
                        hh[r] = h; ll[r] = (_Float16)(v[r] - (float)h);
                    }
                    size_t to = (size_t)gcol * Tstride + grow0;
                    *reinterpret_cast<half4_t*>(&Th[to]) = hh;
                    *reinterpret_cast<half4_t*>(&Tl[to]) = ll;
                }
            } else if (epi == ME_FISTAG || epi == ME_FISTAG_LAST) {
                // A = E so acc = (EZ); GZ = acc + Z. Z_in read from B operand buffer,
                // Z_out -> Th/Tl (distinct ping-pong buffer, race-free)
                size_t to = (size_t)gcol * Tstride + grow0;
                half4_t zh = *reinterpret_cast<const half4_t*>(&Bh[to]);
                half4_t zl = *reinterpret_cast<const half4_t*>(&Bl[to]);
                half4_t oh, ol;
                #pragma unroll
                for (int r = 0; r < 4; ++r) {
                    float z = (float)zh[r] + (float)zl[r];
                    float p = v[r] + z;                          // GZ
                    float bi = BmP[(size_t)(grow0 + r) * NF_ + gcol];
                    rsq = fmaf(z, p - 2.0f * bi, rsq);           // <Z,GZ> - 2<Z,B>
                    float g = z - eta * (p - bi);
                    float gn = softt(g, thr);
                    size_t ci = (size_t)(grow0 + r) * NF_ + gcol;
                    float gold = C[ci];
                    C[ci] = gn;
                    float zo = (epi == ME_FISTAG) ? (gn + betak * (gn - gold)) : gn;
                    _Float16 h = (_Float16)zo;
                    oh[r] = h; ol[r] = (_Float16)(zo - (float)h);
                }
                *reinterpret_cast<half4_t*>(&Th[to]) = oh;
                *reinterpret_cast<half4_t*>(&Tl[to]) = ol;
            } else {   // ME_BIAS / ME_BIASRELU
                if (rowok && colok) {
                    #pragma unroll
                    for (int r = 0; r < 4; ++r) {
                        float s = v[r] + bias[gcol];
                        if (epi == ME_BIASRELU) s = s > 0.f ? s : 0.f;
                        C[(size_t)(grow0 + r) * ldc + gcol] = s;
                    }
                }
            }
        }
    }
    if (epi == ME_FISTAG || epi == ME_FISTAG_LAST) {
        float tot = blockReduceSum(rsq, red);
        if (tid == 0) atomicAdd(nrm_acc, tot);
    }
}

__global__ void logsoftmax_kernel(const float* __restrict__ O, float* __restrict__ out) {
    int row = blockIdx.x * 4 + (threadIdx.x >> 6);
    int lane = threadIdx.x & 63;
    if (row >= NN_) return;
    float v = O[row * NC_ + lane];
    float m = v;
    #pragma unroll
    for (int off = 32; off; off >>= 1) m = fmaxf(m, __shfl_xor(m, off));
    float e = expf(v - m);
    float s = e;
    #pragma unroll
    for (int off = 32; off; off >>= 1) s += __shfl_xor(s, off);
    out[row * NC_ + lane] = (v - m) - logf(s);
}

__global__ void norms_kernel(const float* __restrict__ scal, float* __restrict__ nout) {
    int k = threadIdx.x;
    if (k < FITER) {
        float ysq = scal[4];
        float v = scal[5 + k] + ysq;            // ||WZ-Y||^2 via Gram identity
        nout[k] = sqrtf(fmaxf(v, 0.f)) / sqrtf(ysq);
    }
}

static inline void launch_m(bool afp32, bool three, dim3 grid,
                            const _Float16* Ah, const _Float16* Al,
                            const float* Afp, int Marr,
                            const _Float16* Bh, const _Float16* Bl,
                            int K, int Mvalid, int Nvalid, int ldc,
                            float* C, const float* BmP, const float* bias,
                            _Float16* Th, _Float16* Tl, int Tstride,
                            const float* scal, float betak, float* nrm, int epi,
                            hipStream_t s) {
    if (afp32)
        mgemm_kernel<true, true><<<grid, dim3(256), 0, s>>>(
            Ah, Al, Afp, Marr, Bh, Bl, K, Mvalid, Nvalid, ldc, C, BmP, bias,
            Th, Tl, Tstride, scal, betak, nrm, epi);
    else if (three)
        mgemm_kernel<false, true><<<grid, dim3(256), 0, s>>>(
            Ah, Al, Afp, Marr, Bh, Bl, K, Mvalid, Nvalid, ldc, C, BmP, bias,
            Th, Tl, Tstride, scal, betak, nrm, epi);
    else
        mgemm_kernel<false, false><<<grid, dim3(256), 0, s>>>(
            Ah, Al, Afp, Marr, Bh, Bl, K, Mvalid, Nvalid, ldc, C, BmP, bias,
            Th, Tl, Tstride, scal, betak, nrm, epi);
}

extern "C" void kernel_launch(void* const* d_in, const int* in_sizes, int n_in,
                              void* d_out, int out_size, void* d_ws, size_t ws_size,
                              hipStream_t stream) {
    const float* x     = (const float*)d_in[0];   // (2708, 4096)
    const float* adj   = (const float*)d_in[1];   // (2708, 2708)
    const float* gc1_w = (const float*)d_in[2];   // (4096, 1024)
    const float* gc1_b = (const float*)d_in[3];   // (1024,)
    const float* gc2_w = (const float*)d_in[4];   // (1024, 64)
    const float* gc2_b = (const float*)d_in[5];   // (64,)
    const float* Wd    = (const float*)d_in[6];   // (2708, 2048)
    const int*   Kp    = (const int*)d_in[7];     // scalar K

    float* out = (float*)d_out;
    float* logp    = out;                                     // (2708, 64)
    float* x_dec   = logp + (size_t)NN_ * NC_;                // (2708, 4096)
    float* Gamma   = x_dec + (size_t)NN_ * NF_;               // (2048, 4096)
    float* norms_o = Gamma + (size_t)MD_ * NF_;               // (20,)

    // ---- ws layout: 100,679,808 B (same proven footprint) ----
    char* wsb = (char*)d_ws;
    const size_t OFF_R1 = 16512;                       // after scal/Xa/Xb
    const size_t OFF_R2 = OFF_R1 + 16777216;           // Eh/El (16.78 MB)
    const size_t OFF_R3 = OFF_R2 + 33554432;           // Bm (33.55 MB)
    const size_t OFF_R4 = OFF_R3 + 33554432;           // Wt+xth -> H chain -> ZtA
    float* scal = (float*)wsb;
    float* Xa   = scal + 32;
    float* Xb   = Xa + MD_;
    _Float16* Eh = (_Float16*)(wsb + OFF_R1);          // E = G - I, split
    _Float16* El = Eh + (size_t)MD_ * MD_;
    float* Bm = (float*)(wsb + OFF_R2);
    // R3 phase 1: Wt + xth_hi
    _Float16* Wt_hi  = (_Float16*)(wsb + OFF_R3);
    _Float16* Wt_lo  = Wt_hi + (size_t)MD_ * KPAD;
    _Float16* xth_hi = Wt_lo + (size_t)MD_ * KPAD;     // 11.14 MB, fits slack
    _Float16* xth_lo = (_Float16*)(wsb + OFF_R4);      // R4 phase 1 (11.14 <= 16.78)
    // H squaring chain ping-pong: HA in R4 (16.78 MB), HB in first 16.78 MB of R3
    _Float16* HA_hi = (_Float16*)(wsb + OFF_R4);
    _Float16* HA_lo = HA_hi + (size_t)MD_ * MD_;
    _Float16* HB_hi = (_Float16*)(wsb + OFF_R3);
    _Float16* HB_lo = HB_hi + (size_t)MD_ * MD_;
    // R3 phase 2: ZtA (4096 x 2048 split, ping) — after power2 consumes H5 (in HA)
    _Float16* ZA_hi = (_Float16*)(wsb + OFF_R3);
    _Float16* ZA_lo = ZA_hi + (size_t)NF_ * MD_;
    // pong: the x_dec slab of d_out (44.4 MB >= 33.55 MB), scratch until phase 3
    _Float16* ZB_hi = (_Float16*)x_dec;
    _Float16* ZB_lo = ZB_hi + (size_t)NF_ * MD_;
    // phase 3:
    _Float16* adjT_hi = (_Float16*)(wsb + OFF_R2);                 // [2816][2720] hi, 15.3 MB
    _Float16* xwT_hi  = (_Float16*)(wsb + OFF_R2 + 15319040);      // [1024][2720] split, 11.1 MB
    _Float16* xwT_lo  = xwT_hi + (size_t)NH_ * KPAD;
    _Float16* g1t_hi  = (_Float16*)(wsb + OFF_R1);                 // [1024][4096] split
    _Float16* g1t_lo  = g1t_hi + (size_t)NH_ * NF_;
    _Float16* xdh     = (_Float16*)(wsb + OFF_R3);                 // [2816][4096] hi, 23.1 MB
    float*    hbuf    = (float*)(wsb + OFF_R3);                    // [2708][1024] fp32 (after xdh dead)
    _Float16* Wh      = (_Float16*)(wsb + OFF_R4);                 // [2816][2048] hi, 11.5 MB
    _Float16* g2t_hi  = (_Float16*)(wsb + OFF_R4 + 11534336);      // [128][1024] split
    _Float16* g2t_lo  = g2t_hi + (size_t)128 * NH_;
    _Float16* hwT_hi  = (_Float16*)(wsb + OFF_R4 + 12058624);      // [128][2720] split
    _Float16* hwT_lo  = hwT_hi + (size_t)128 * KPAD;
    float*    obuf    = (float*)(wsb + OFF_R4 + 13451264);         // [2708][64]

    const _Float16* nullh = nullptr;
    float* nullf = nullptr;

    // ---- phase 1: init, E = W^T W - I, B = W^T Y, squaring chain, power, Gamma0 ----
    zero_scal_kernel<<<1, 64, 0, stream>>>(scal);
    init_x0_kernel<<<4, 256, 0, stream>>>(Xa);
    sumsq_kernel<<<1024, 256, 0, stream>>>(x, NN_ * NF_, scal + 4);

    tsplit_kernel<<<dim3(MD_ / 32, KPAD / 32), 256, 0, stream>>>(Wd, NN_, MD_, KPAD, Wt_hi, Wt_lo);
    // E = W^T W - I (3-product: E is the 24x-applied operator, keep full precision)
    launch_m(false, true, dim3(16, 16), Wt_hi, Wt_lo, nullptr, 0, Wt_hi, Wt_lo,
             KPAD, MD_, MD_, 0, nullf, nullptr, nullptr, Eh, El, MD_,
             scal, 0.f, nullptr, ME_SYMSPLIT_MI, stream);
    // B = W^T Y in two N-halves (2-product: Wh·(Yh+Yl))
    for (int half = 0; half < 2; ++half) {
        tsplit_kernel<<<dim3(MD_ / 32, KPAD / 32), 256, 0, stream>>>(
            x + half * 2048, NN_, NF_, KPAD, xth_hi, xth_lo);
        launch_m(false, false, dim3(16, 16), Wt_hi, Wt_lo, nullptr, 0, xth_hi, xth_lo,
                 KPAD, MD_, MD_, NF_, Bm + half * 2048, nullptr, nullptr,
                 nullptr, nullptr, 0, scal, 0.f, nullptr, ME_STORE, stream);
    }
    // squaring chain (2-product): H1=G^2/16, H2=H1^2, H3=H2^2, H4=H3^2, H5=16*H4^2 (=G^32/2^60)
    launch_m(false, false, dim3(16, 16), Eh, El, nullptr, 0, Eh, El,
             MD_, MD_, MD_, 0, nullf, nullptr, nullptr, HA_hi, HA_lo, MD_,
             scal, 0.f, nullptr, ME_H1, stream);
    launch_m(false, false, dim3(16, 16), HA_hi, HA_lo, nullptr, 0, HA_hi, HA_lo,
             MD_, MD_, MD_, 0, nullf, nullptr, nullptr, HB_hi, HB_lo, MD_,
             scal, 0.f, nullptr, ME_SYMSPLIT, stream);
    launch_m(false, false, dim3(16, 16), HB_hi, HB_lo, nullptr, 0, HB_hi, HB_lo,
             MD_, MD_, MD_, 0, nullf, nullptr, nullptr, HA_hi, HA_lo, MD_,
             scal, 0.f, nullptr, ME_SYMSPLIT, stream);
    launch_m(false, false, dim3(16, 16), HA_hi, HA_lo, nullptr, 0, HA_hi, HA_lo,
             MD_, MD_, MD_, 0, nullf, nullptr, nullptr, HB_hi, HB_lo, MD_,
             scal, 0.f, nullptr, ME_SYMSPLIT, stream);
    launch_m(false, false, dim3(16, 16), HB_hi, HB_lo, nullptr, 0, HB_hi, HB_lo,
             MD_, MD_, MD_, 0, nullf, nullptr, nullptr, HA_hi, HA_lo, MD_,
             scal, 0.f, nullptr, ME_SYMSPLIT16, stream);
    // cooperative power: 3x H5 + 4x G (= exactly 100 G-applies)
    {
        void* args[] = {(void*)&HA_hi, (void*)&HA_lo, (void*)&Eh, (void*)&El,
                        (void*)&Kp, (void*)&scal, (void*)&Xa, (void*)&Xb};
        hipLaunchCooperativeKernel((void*)power2_kernel, dim3(256), dim3(256), args, 0, stream);
    }
    // Gamma0 = soft(eta*B, lam); ZtA = split(Gamma0^T)  (overwrites HB — dead now)
    g0_kernel<<<dim3(NF_ / 32, MD_ / 32), 256, 0, stream>>>(Bm, scal, Gamma, ZA_hi, ZA_lo);

    // ---- phase 2: FISTA in Gram domain, A = E (2-product), Z ping-pong ----
    {
        float t = 1.f;
        for (int k = 0; k < FITER; ++k) {
            float tn = (1.0f + sqrtf(1.0f + (4.0f * t) * t)) / 2.0f;
            float beta = (t - 1.0f) / tn;
            t = tn;
            _Float16* in_hi  = (k & 1) ? ZB_hi : ZA_hi;
            _Float16* in_lo  = (k & 1) ? ZB_lo : ZA_lo;
            _Float16* out_hi = (k & 1) ? ZA_hi : ZB_hi;
            _Float16* out_lo = (k & 1) ? ZA_lo : ZB_lo;
            launch_m(false, false, dim3(32, 16), Eh, El, nullptr, 0, in_hi, in_lo,
                     MD_, MD_, NF_, NF_, Gamma, Bm, nullptr,
                     out_hi, out_lo, MD_, scal, beta, scal + 5 + k,
                     (k == FITER - 1) ? ME_FISTAG_LAST : ME_FISTAG, stream);
        }
        // FITER=20 even: final Gamma-split lands in ZA (ws); ZB (x_dec slab) is dead
    }

    // ---- phase 3: decode + GCN tail (all 2-product staged MFMA) ----
    splitadj_hi_kernel<<<2816, 256, 0, stream>>>(adj, adjT_hi);        // Bm dead now
    splitrows_hi_kernel<<<2816, 256, 0, stream>>>(Wd, NN_, MD_, Wh);
    // x_dec = W @ Gamma : A = Wh (2-product), B = ZA (Gamma^T split)
    launch_m(false, false, dim3(32, 22), Wh, Wh, nullptr, 0, ZA_hi, ZA_lo,
             MD_, NN_, NF_, NF_, x_dec, nullptr, nullptr,
             nullptr, nullptr, 0, scal, 0.f, nullptr, ME_STORE, stream);
    // xdh = hi(x_dec), overwrites dead ZA
    splitrows_hi_kernel<<<2816, 256, 0, stream>>>(x_dec, NN_, NF_, xdh);
    tsplit_kernel<<<dim3(NH_ / 32, NF_ / 32), 256, 0, stream>>>(gc1_w, NF_, NH_, NF_, g1t_hi, g1t_lo);
    fill0_kernel<<<(2785280 + 255) / 256, 256, 0, stream>>>((uint32_t*)xwT_hi, 2785280);
    // xw^T = split((x_dec @ gc1_w)^T) : A = xdh (2-product)
    launch_m(false, false, dim3(8, 22), xdh, xdh, nullptr, 0, g1t_hi, g1t_lo,
             NF_, NN_, NH_, 0, nullf, nullptr, nullptr,
             xwT_hi, xwT_lo, KPAD, scal, 0.f, nullptr, ME_SPLIT_T, stream);
    // h = relu(adj @ xw + b1) : A = adjT_hi (2-product); hbuf overwrites dead xdh
    launch_m(false, false, dim3(8, 22), adjT_hi, adjT_hi, nullptr, 0, xwT_hi, xwT_lo,
             KPAD, NN_, NH_, NH_, hbuf, nullptr, gc1_b,
             nullptr, nullptr, 0, scal, 0.f, nullptr, ME_BIASRELU, stream);
    fill0_kernel<<<(131072 + 255) / 256, 256, 0, stream>>>((uint32_t*)g2t_hi, 131072);
    tsplit_kernel<<<dim3(NC_ / 32, NH_ / 32), 256, 0, stream>>>(gc2_w, NH_, NC_, NH_, g2t_hi, g2t_lo);
    fill0_kernel<<<(348160 + 255) / 256, 256, 0, stream>>>((uint32_t*)hwT_hi, 348160);
    // hw^T = split((h @ gc2_w)^T) : tiny, keep AFP32 3-product
    launch_m(true, true, dim3(1, 22), nullh, nullh, hbuf, NN_, g2t_hi, g2t_lo,
             NH_, NN_, NC_, 0, nullf, nullptr, nullptr,
             hwT_hi, hwT_lo, KPAD, scal, 0.f, nullptr, ME_SPLIT_T, stream);
    // o = adj @ hw + b2 : A = adjT_hi (2-product)
    launch_m(false, false, dim3(1, 22), adjT_hi, adjT_hi, nullptr, 0, hwT_hi, hwT_lo,
             KPAD, NN_, NC_, NC_, obuf, nullptr, gc2_b,
             nullptr, nullptr, 0, scal, 0.f, nullptr, ME_BIAS, stream);
    logsoftmax_kernel<<<(NN_ + 3) / 4, 256, 0, stream>>>(obuf, logp);
    norms_kernel<<<1, 32, 0, stream>>>(scal, norms_o);
}